// Round 1
// 5260.544 us; speedup vs baseline: 5.5033x; 5.5033x over previous
//
#include <hip/hip_runtime.h>
#include <hip/hip_bf16.h>
#include <math.h>

typedef __hip_bfloat16 bf16;

// ---------- dtype-adaptive load/store (bf=1 -> bf16, bf=0 -> fp32) ----------
__device__ __forceinline__ float ldf(const void* p, size_t i, int bf) {
    if (bf) return __bfloat162float(((const bf16*)p)[i]);
    return ((const float*)p)[i];
}
__device__ __forceinline__ void stf(void* p, size_t i, int bf, float v) {
    if (bf) ((bf16*)p)[i] = __float2bfloat16(v);
    else    ((float*)p)[i] = v;
}

// ---------- dtype detector: vote on exponent-byte signature of fp1_p2 ----------
__global__ void k_detect(const void* __restrict__ probe, int* __restrict__ flag) {
    if (threadIdx.x == 0 && blockIdx.x == 0) {
        const unsigned int* w = (const unsigned int*)probe;
        int hits = 0;
        for (int i = 0; i < 256; ++i) {
            unsigned int hb = (w[i] >> 8) & 0x7Fu;   // bf16: exp[7:1] of low element
            if (hb >= 0x3Bu && hb <= 0x40u) ++hits;  // N(0,1) exponent band
        }
        *flag = (hits >= 128) ? 1 : 0;               // 1 = bf16, 0 = fp32
    }
}

// ---------- weight transpose to fp32: dst[f*Eout+e] = src[e*Ein+f] ----------
// src is [Eout x Ein] row-major (possibly bf16); dst is [Ein x Eout] fp32.
__global__ void k_wt(const void* __restrict__ src, float* __restrict__ dst,
                     const int* __restrict__ dflag, int Eout, int Ein)
{
    int bf = *dflag;
    int idx = blockIdx.x * blockDim.x + threadIdx.x;
    int total = Eout * Ein;
    if (idx >= total) return;
    int e = idx / Ein, f = idx - e * Ein;
    dst[(size_t)f * Eout + e] = ldf(src, (size_t)idx, bf);
}

// ---------- stitch index map (derived from the reference reshape chain) ----------
__device__ __forceinline__ void stitch_map(int y, int x, int s, int nh, int nw,
                                           int& n, int& e)
{
    int px = x % s;
    int d0 = x / s;
    int M  = d0 * (nh * s) + y;
    int py = M / (nw * nh);
    int rem = M - py * (nw * nh);
    int iw = rem / nh;
    int ih = rem - iw * nh;
    n = ih * nw + iw;
    e = py * s + px;
}

// ---------- patchify (+ optional align-corners bilinear up-resize) ----------
__global__ void k_patchify(const void* __restrict__ fp1, const void* __restrict__ fp2,
                           float* __restrict__ qb, float* __restrict__ pb,
                           const int* __restrict__ dflag,
                           int bc0, int chunk, int N, int E, int s, int nh, int nw,
                           int h_, int w_, int h, int w, int resize)
{
    int bf = *dflag;
    int idx = blockIdx.x * blockDim.x + threadIdx.x;
    int total = chunk * N * E;
    if (idx >= total) return;
    int e = idx % E; int t = idx / E;
    int n = t % N;   int i = t / N;
    int ih = n / nw, iw = n - ih * nw;
    int py = e / s,  px = e - py * s;
    int Y = ih * s + py, X = iw * s + px;
    size_t base = (size_t)(bc0 + i) * h_ * w_;
    float v1, v2;
    if (!resize) {
        size_t off = base + (size_t)Y * w_ + X;
        v1 = ldf(fp1, off, bf); v2 = ldf(fp2, off, bf);
    } else {
        float fy = (float)Y * ((float)(h_ - 1) / (float)(h - 1));
        float fx = (float)X * ((float)(w_ - 1) / (float)(w - 1));
        int y0 = (int)floorf(fy); int x0 = (int)floorf(fx);
        float wy = fy - (float)y0, wx = fx - (float)x0;
        int y1 = min(y0 + 1, h_ - 1), x1 = min(x0 + 1, w_ - 1);
        size_t r0 = base + (size_t)y0 * w_, r1 = base + (size_t)y1 * w_;
        {
            float a00 = ldf(fp1, r0 + x0, bf), a01 = ldf(fp1, r0 + x1, bf);
            float a10 = ldf(fp1, r1 + x0, bf), a11 = ldf(fp1, r1 + x1, bf);
            v1 = (a00 * (1.f - wy) + a10 * wy) * (1.f - wx)
               + (a01 * (1.f - wy) + a11 * wy) * wx;
        }
        {
            float a00 = ldf(fp2, r0 + x0, bf), a01 = ldf(fp2, r0 + x1, bf);
            float a10 = ldf(fp2, r1 + x0, bf), a11 = ldf(fp2, r1 + x1, bf);
            v2 = (a00 * (1.f - wy) + a10 * wy) * (1.f - wx)
               + (a01 * (1.f - wy) + a11 * wy) * wx;
        }
    }
    qb[idx] = v1;
    pb[idx] = v2;
}

// ---------- fused Q,K,V projection (coalesced transposed weights) ----------
// block = E threads, R rows per block. Writes Q,V row-major; K transposed
// per item: Kt[(i*E + e)*N + n]  (so k_scores2 reads it coalesced).
template<int R>
__global__ void k_qkv2(const float* __restrict__ qb, const float* __restrict__ pb,
                       float* __restrict__ Q, float* __restrict__ Kt, float* __restrict__ V,
                       const float* __restrict__ qwT, const float* __restrict__ kwT,
                       const float* __restrict__ vwT, const void* __restrict__ inb,
                       const int* __restrict__ dflag, int N, int E)
{
    constexpr int RP = (R & 1) ? R : R + 1;   // odd stride -> conflict-free staging
    int bf = *dflag;
    int e = threadIdx.x;                       // [0, E)
    long row0 = (long)blockIdx.x * R;          // R | N so a block never straddles items
    int i  = (int)(row0 / N);
    int n0 = (int)(row0 - (long)i * N);
    extern __shared__ float sm[];              // transposed: sq[f*RP+r], sp[f*RP+r]
    float* sq = sm;
    float* sp = sm + (size_t)E * RP;
#pragma unroll
    for (int r = 0; r < R; ++r) {
        sq[(size_t)e * RP + r] = qb[(row0 + r) * (size_t)E + e];
        sp[(size_t)e * RP + r] = pb[(row0 + r) * (size_t)E + e];
    }
    __syncthreads();
    float aQ[R], aK[R], aV[R];
    float biQ = ldf(inb, e, bf), biK = ldf(inb, E + e, bf), biV = ldf(inb, 2 * E + e, bf);
#pragma unroll
    for (int r = 0; r < R; ++r) { aQ[r] = biQ; aK[r] = biK; aV[r] = biV; }
    const float* qwp = qwT + e;                         // wT[f*E + e]: coalesced
    const float* kp1 = kwT + e;
    const float* kp2 = kwT + (size_t)E * E + e;
    const float* vp1 = vwT + e;
    const float* vp2 = vwT + (size_t)E * E + e;
#pragma unroll 2
    for (int f = 0; f < E; ++f) {
        float wq  = qwp[(size_t)f * E];
        float wk1 = kp1[(size_t)f * E];
        float wk2 = kp2[(size_t)f * E];
        float wv1 = vp1[(size_t)f * E];
        float wv2 = vp2[(size_t)f * E];
#pragma unroll
        for (int r = 0; r < R; ++r) {
            float qf = sq[(size_t)f * RP + r];   // broadcast (free)
            float pf = sp[(size_t)f * RP + r];
            aQ[r] += qf * wq;
            aK[r] += qf * wk1 + pf * wk2;
            aV[r] += qf * wv1 + pf * wv2;
        }
    }
#pragma unroll
    for (int r = 0; r < R; ++r) {
        size_t o = (row0 + r) * (size_t)E + e;
        Q[o] = aQ[r]; V[o] = aV[r];
    }
    float* ktp = Kt + ((size_t)i * E + e) * N + n0;     // contiguous R floats/thread
    if constexpr ((R & 3) == 0) {
        if ((N & 3) == 0) {                             // alignment provable: n0 % R == 0
#pragma unroll
            for (int r4 = 0; r4 < R / 4; ++r4)
                *(float4*)(ktp + 4 * r4) =
                    make_float4(aK[4*r4], aK[4*r4+1], aK[4*r4+2], aK[4*r4+3]);
        } else {
            for (int r = 0; r < R; ++r) ktp[r] = aK[r];
        }
    } else {
        for (int r = 0; r < R; ++r) ktp[r] = aK[r];
    }
}

// ---------- scores + softmax: block = N threads, R rows (R divides N) ----------
// K is consumed transposed: Kt[(i*E+e)*N + m] -> coalesced across threads m.
template<int R>
__global__ void k_scores2(const float* __restrict__ Q, const float* __restrict__ Kt,
                          float* __restrict__ A, int N, int E, float scale)
{
    constexpr int RP = (R & 1) ? R : R + 1;
    int m = threadIdx.x;                 // [0, N)
    long row0 = (long)blockIdx.x * R;
    int i = (int)(row0 / N);
    extern __shared__ float sm[];        // sq[E*RP] transposed + sred[N]
    float* sq   = sm;
    float* sred = sm + (size_t)E * RP;
    for (int r = 0; r < R; ++r)
        for (int e = m; e < E; e += N)
            sq[(size_t)e * RP + r] = Q[(row0 + r) * (size_t)E + e];
    __syncthreads();
    const float* Kb = Kt + (size_t)i * E * N + m;
    float acc[R];
#pragma unroll
    for (int r = 0; r < R; ++r) acc[r] = 0.f;
#pragma unroll 2
    for (int e = 0; e < E; ++e) {
        float kv = Kb[(size_t)e * N];
#pragma unroll
        for (int r = 0; r < R; ++r) acc[r] += sq[(size_t)e * RP + r] * kv;
    }
#pragma unroll
    for (int r = 0; r < R; ++r) acc[r] *= scale;
    for (int r = 0; r < R; ++r) {
        sred[m] = acc[r]; __syncthreads();
        for (int cnt = N; cnt > 1; ) {
            int half = (cnt + 1) >> 1;
            if (m < cnt - half) sred[m] = fmaxf(sred[m], sred[m + half]);
            __syncthreads();
            cnt = half;
        }
        float mx = sred[0]; __syncthreads();
        float ev = __expf(acc[r] - mx);
        sred[m] = ev; __syncthreads();
        for (int cnt = N; cnt > 1; ) {
            int half = (cnt + 1) >> 1;
            if (m < cnt - half) sred[m] += sred[m + half];
            __syncthreads();
            cnt = half;
        }
        float sum = sred[0]; __syncthreads();
        A[(row0 + r) * (size_t)N + m] = ev / sum;
    }
}

// ---------- O = A @ V: block = E threads, R rows (R divides N) ----------
template<int R>
__global__ void k_av(const float* __restrict__ A, const float* __restrict__ V,
                     float* __restrict__ O, int N, int E)
{
    constexpr int RP = (R & 1) ? R : R + 1;
    int e = threadIdx.x;                 // [0, E)
    long row0 = (long)blockIdx.x * R;
    int i = (int)(row0 / N);
    extern __shared__ float sm[];        // sa[N*RP] transposed
    for (int r = 0; r < R; ++r)
        for (int m = e; m < N; m += E)
            sm[(size_t)m * RP + r] = A[(row0 + r) * (size_t)N + m];
    __syncthreads();
    const float* Vb = V + (size_t)i * N * E;
    float acc[R];
#pragma unroll
    for (int r = 0; r < R; ++r) acc[r] = 0.f;
#pragma unroll 2
    for (int m = 0; m < N; ++m) {
        float vv = Vb[(size_t)m * E + e];     // coalesced across e
#pragma unroll
        for (int r = 0; r < R; ++r) acc[r] += sm[(size_t)m * RP + r] * vv;
    }
#pragma unroll
    for (int r = 0; r < R; ++r) O[(row0 + r) * (size_t)E + e] = acc[r];
}

// ---------- out-proj + LayerNorm (coalesced transposed weight) ----------
template<int R>
__global__ void k_projln2(const float* __restrict__ O, float* __restrict__ O2,
                          const float* __restrict__ owT, const void* __restrict__ ob,
                          const void* __restrict__ lng, const void* __restrict__ lnb,
                          const int* __restrict__ dflag, int E)
{
    constexpr int RP = (R & 1) ? R : R + 1;
    int bf = *dflag;
    int e = threadIdx.x;
    long row0 = (long)blockIdx.x * R;
    extern __shared__ float sm[];        // so[E*RP] transposed + sred[E]
    float* so   = sm;
    float* sred = sm + (size_t)E * RP;
    for (int r = 0; r < R; ++r)
        so[(size_t)e * RP + r] = O[(row0 + r) * (size_t)E + e];
    __syncthreads();
    float acc[R];
    float bo = ldf(ob, e, bf);
#pragma unroll
    for (int r = 0; r < R; ++r) acc[r] = bo;
    const float* owp = owT + e;
#pragma unroll 2
    for (int f = 0; f < E; ++f) {
        float w = owp[(size_t)f * E];    // coalesced
#pragma unroll
        for (int r = 0; r < R; ++r) acc[r] += so[(size_t)f * RP + r] * w;
    }
    float g = ldf(lng, e, bf), bta = ldf(lnb, e, bf);
    for (int r = 0; r < R; ++r) {
        sred[e] = acc[r]; __syncthreads();
        for (int cnt = E; cnt > 1; ) {
            int half = (cnt + 1) >> 1;
            if (e < cnt - half) sred[e] += sred[e + half];
            __syncthreads();
            cnt = half;
        }
        float mu = sred[0] / (float)E; __syncthreads();
        float d = acc[r] - mu;
        sred[e] = d * d; __syncthreads();
        for (int cnt = E; cnt > 1; ) {
            int half = (cnt + 1) >> 1;
            if (e < cnt - half) sred[e] += sred[e + half];
            __syncthreads();
            cnt = half;
        }
        float var = sred[0] / (float)E; __syncthreads();
        O2[(row0 + r) * (size_t)E + e] = d * rsqrtf(var + 1e-5f) * g + bta;
    }
}

// ---------- final blend, no-resize levels ----------
__global__ void k_final(const float* __restrict__ O2,
                        const void* __restrict__ fp1, const void* __restrict__ fp2,
                        const void* __restrict__ logits, void* __restrict__ out,
                        const int* __restrict__ dflag, size_t obase,
                        int bc0, int chunk, int h, int w, int s, int nh, int nw,
                        int N, int E)
{
    int bf = *dflag;
    int idx = blockIdx.x * blockDim.x + threadIdx.x;
    int total = chunk * h * w;
    if (idx >= total) return;
    int x = idx % w; int t = idx / w;
    int y = t % h;   int i = t / h;
    int n, e;
    stitch_map(y, x, s, nh, nw, n, e);
    float fus = O2[((size_t)i * N + n) * E + e];
    float l0 = ldf(logits, 0, bf), l1 = ldf(logits, 1, bf), l2 = ldf(logits, 2, bf);
    float mx = fmaxf(l0, fmaxf(l1, l2));
    float e0 = __expf(l0 - mx), e1 = __expf(l1 - mx), e2 = __expf(l2 - mx);
    float inv = 1.f / (e0 + e1 + e2);
    size_t off = ((size_t)(bc0 + i) * h + y) * w + x;
    float v = ldf(fp1, off, bf) * (e0 * inv) + ldf(fp2, off, bf) * (e1 * inv)
            + fus * (e2 * inv);
    stf(out, obase + off, bf, v);
}

// ---------- stitch to full (rounded) grid, fp32 (p3 only) ----------
__global__ void k_stitch(const float* __restrict__ O2, float* __restrict__ st,
                         int chunk, int h, int w, int s, int nh, int nw, int N, int E)
{
    int idx = blockIdx.x * blockDim.x + threadIdx.x;
    int total = chunk * h * w;
    if (idx >= total) return;
    int x = idx % w; int t = idx / w;
    int y = t % h;   int i = t / h;
    int n, e;
    stitch_map(y, x, s, nh, nw, n, e);
    st[idx] = O2[((size_t)i * N + n) * E + e];
}

// ---------- down-resize (align corners) + blend (p3 only) ----------
__global__ void k_rblend(const float* __restrict__ st,
                         const void* __restrict__ fp1, const void* __restrict__ fp2,
                         const void* __restrict__ logits, void* __restrict__ out,
                         const int* __restrict__ dflag, size_t obase,
                         int bc0, int chunk, int h_, int w_, int h, int w)
{
    int bf = *dflag;
    int idx = blockIdx.x * blockDim.x + threadIdx.x;
    int total = chunk * h_ * w_;
    if (idx >= total) return;
    int x = idx % w_; int t = idx / w_;
    int y = t % h_;   int i = t / h_;
    float fy = (float)y * ((float)(h - 1) / (float)(h_ - 1));
    float fx = (float)x * ((float)(w - 1) / (float)(w_ - 1));
    int y0 = (int)floorf(fy); int x0 = (int)floorf(fx);
    float wy = fy - (float)y0, wx = fx - (float)x0;
    int y1 = min(y0 + 1, h - 1), x1 = min(x0 + 1, w - 1);
    size_t base = (size_t)i * h * w;
    float a00 = st[base + (size_t)y0 * w + x0], a01 = st[base + (size_t)y0 * w + x1];
    float a10 = st[base + (size_t)y1 * w + x0], a11 = st[base + (size_t)y1 * w + x1];
    float fus = (a00 * (1.f - wy) + a10 * wy) * (1.f - wx)
              + (a01 * (1.f - wy) + a11 * wy) * wx;
    float l0 = ldf(logits, 0, bf), l1 = ldf(logits, 1, bf), l2 = ldf(logits, 2, bf);
    float mx = fmaxf(l0, fmaxf(l1, l2));
    float e0 = __expf(l0 - mx), e1 = __expf(l1 - mx), e2 = __expf(l2 - mx);
    float inv = 1.f / (e0 + e1 + e2);
    size_t off = ((size_t)(bc0 + i) * h_ + y) * w_ + x;
    float v = ldf(fp1, off, bf) * (e0 * inv) + ldf(fp2, off, bf) * (e1 * inv)
            + fus * (e2 * inv);
    stf(out, obase + off, bf, v);
}

extern "C" void kernel_launch(void* const* d_in, const int* in_sizes, int n_in,
                              void* d_out, int out_size, void* d_ws, size_t ws_size,
                              hipStream_t stream)
{
    (void)in_sizes; (void)n_in; (void)out_size;
    const void* FP1[5]; const void* FP2[5];
    const void *QW[5], *KW[5], *VW[5], *INB[5], *OW[5], *OB[5], *LNG[5], *LNB[5];
    for (int l = 0; l < 5; ++l) {
        FP1[l] = d_in[l];
        FP2[l] = d_in[5 + l];
        int b = 10 + 8 * l;
        QW[l]  = d_in[b + 0];
        KW[l]  = d_in[b + 1];
        VW[l]  = d_in[b + 2];
        INB[l] = d_in[b + 3];
        OW[l]  = d_in[b + 4];
        OB[l]  = d_in[b + 5];
        LNG[l] = d_in[b + 6];
        LNB[l] = d_in[b + 7];
    }
    const void* logits = d_in[50];
    void* out = d_out;

    static const int HH[5] = {256, 128, 64, 32, 16};
    static const int SS[5] = {16, 12, 8, 4, 2};

    // ws layout: [6 fp32 slots][2MB transposed-weight region][dtype flag (16B)]
    size_t flag_off = (ws_size - 16) & ~(size_t)15;
    int* dflag = (int*)((char*)d_ws + flag_off);
    const size_t WRES = (size_t)2 * 1024 * 1024;       // max 6*E^2*4 = 1.5MB at p2
    size_t wreg_off = (flag_off > WRES) ? ((flag_off - WRES) & ~(size_t)255) : 0;
    float* wreg = (float*)((char*)d_ws + wreg_off);
    size_t slot_bytes = (wreg_off / 6) & ~(size_t)255;
    size_t slot_elems = slot_bytes / sizeof(float);
    float* slot[6];
    for (int i = 0; i < 6; ++i) slot[i] = (float*)((char*)d_ws + (size_t)i * slot_bytes);

    k_detect<<<1, 64, 0, stream>>>(FP1[0], dflag);

    size_t ooff = 0;
    for (int l = 0; l < 5; ++l) {
        int h_ = HH[l], w_ = HH[l], s = SS[l];
        int nh = (h_ % s == 0) ? (h_ / s) : (h_ / s + 1);
        int nw = nh;
        int h = nh * s, w = nw * s;
        int N = nh * nw, E = s * s;
        int resize = (h != h_) ? 1 : 0;
        int Rq = (l == 1) ? 11 : 16;    // qkv rows/block, must divide N
        int Rr = (l == 1) ? 11 : 8;     // scores/av/projln rows/block
        int RPq = (Rq & 1) ? Rq : Rq + 1;
        int RPr = (Rr & 1) ? Rr : Rr + 1;
        float scale = 1.0f / sqrtf((float)E);
        size_t maxNE = (size_t)N * (size_t)((E > N) ? E : N);

        // one-time per-level weight transpose into fp32 (stream-ordered: the
        // region is safely reused because levels run sequentially)
        float* wqT = wreg;
        float* wkT = wqT + (size_t)E * E;        // [2E x E]
        float* wvT = wkT + (size_t)2 * E * E;    // [2E x E]
        float* woT = wvT + (size_t)2 * E * E;    // [E x E]
        {
            int tpb = 256;
            k_wt<<<(E * E + tpb - 1) / tpb, tpb, 0, stream>>>(QW[l], wqT, dflag, E, E);
            k_wt<<<(2 * E * E + tpb - 1) / tpb, tpb, 0, stream>>>(KW[l], wkT, dflag, E, 2 * E);
            k_wt<<<(2 * E * E + tpb - 1) / tpb, tpb, 0, stream>>>(VW[l], wvT, dflag, E, 2 * E);
            k_wt<<<(E * E + tpb - 1) / tpb, tpb, 0, stream>>>(OW[l], woT, dflag, E, E);
        }

        int chunk = 512;
        size_t c = (maxNE > 0) ? (slot_elems / maxNE) : 0;
        if (c < 512) { int p = 1; while ((size_t)(p << 1) <= c) p <<= 1; chunk = p; }
        int nchunks = 512 / chunk;

        for (int cidx = 0; cidx < nchunks; ++cidx) {
            int bc0 = cidx * chunk;
            int rows = chunk * N;
            int blocksQ = rows / Rq;
            int blocksR = rows / Rr;
            // 1) patchify
            {
                int tot = chunk * N * E, tpb = 256, g = (tot + tpb - 1) / tpb;
                k_patchify<<<g, tpb, 0, stream>>>(FP1[l], FP2[l], slot[0], slot[1],
                                                  dflag, bc0, chunk, N, E, s, nh, nw,
                                                  h_, w_, h, w, resize);
            }
            // 2) QKV (writes Q, Kt (transposed per item), V)
            {
                size_t sh = (size_t)2 * RPq * E * sizeof(float);
                if (Rq == 16)
                    k_qkv2<16><<<blocksQ, E, sh, stream>>>(slot[0], slot[1], slot[2], slot[3], slot[4],
                                                           wqT, wkT, wvT, INB[l], dflag, N, E);
                else
                    k_qkv2<11><<<blocksQ, E, sh, stream>>>(slot[0], slot[1], slot[2], slot[3], slot[4],
                                                           wqT, wkT, wvT, INB[l], dflag, N, E);
            }
            // 3) scores + softmax (reads Kt coalesced)
            {
                size_t sh = ((size_t)RPr * E + N) * sizeof(float);
                if (Rr == 8)
                    k_scores2<8><<<blocksR, N, sh, stream>>>(slot[2], slot[3], slot[5], N, E, scale);
                else
                    k_scores2<11><<<blocksR, N, sh, stream>>>(slot[2], slot[3], slot[5], N, E, scale);
            }
            // 4) O = A @ V
            {
                size_t sh = (size_t)RPr * N * sizeof(float);
                if (Rr == 8)
                    k_av<8><<<blocksR, E, sh, stream>>>(slot[5], slot[4], slot[0], N, E);
                else
                    k_av<11><<<blocksR, E, sh, stream>>>(slot[5], slot[4], slot[0], N, E);
            }
            // 5) out-proj + LN
            {
                size_t sh = ((size_t)RPr * E + E) * sizeof(float);
                if (Rr == 8)
                    k_projln2<8><<<blocksR, E, sh, stream>>>(slot[0], slot[1], woT,
                                                             OB[l], LNG[l], LNB[l], dflag, E);
                else
                    k_projln2<11><<<blocksR, E, sh, stream>>>(slot[0], slot[1], woT,
                                                              OB[l], LNG[l], LNB[l], dflag, E);
            }
            // 6) stitch (+resize) + blend
            if (!resize) {
                int tot = chunk * h * w, tpb = 256, g = (tot + tpb - 1) / tpb;
                k_final<<<g, tpb, 0, stream>>>(slot[1], FP1[l], FP2[l], logits, out,
                                               dflag, ooff, bc0, chunk, h, w, s, nh, nw, N, E);
            } else {
                int tot = chunk * h * w, tpb = 256, g = (tot + tpb - 1) / tpb;
                k_stitch<<<g, tpb, 0, stream>>>(slot[1], slot[2], chunk, h, w, s, nh, nw, N, E);
                int tot2 = chunk * h_ * w_, g2 = (tot2 + tpb - 1) / tpb;
                k_rblend<<<g2, tpb, 0, stream>>>(slot[2], FP1[l], FP2[l], logits, out,
                                                 dflag, ooff, bc0, chunk, h_, w_, h, w);
            }
        }
        ooff += (size_t)512 * h_ * w_;
    }
}

// Round 2
// 5173.655 us; speedup vs baseline: 5.5957x; 1.0168x over previous
//
#include <hip/hip_runtime.h>
#include <hip/hip_bf16.h>
#include <math.h>

typedef __hip_bfloat16 bf16;
typedef __attribute__((ext_vector_type(8))) short short8v;
typedef __attribute__((ext_vector_type(4))) float float4v;

// ---------- dtype-adaptive load/store (bf=1 -> bf16, bf=0 -> fp32) ----------
__device__ __forceinline__ float ldf(const void* p, size_t i, int bf) {
    if (bf) return __bfloat162float(((const bf16*)p)[i]);
    return ((const float*)p)[i];
}
__device__ __forceinline__ void stf(void* p, size_t i, int bf, float v) {
    if (bf) ((bf16*)p)[i] = __float2bfloat16(v);
    else    ((float*)p)[i] = v;
}
__device__ __forceinline__ unsigned short f2bf_bits(float x) {
    __hip_bfloat16 h = __float2bfloat16(x);
    union { __hip_bfloat16 hh; unsigned short us; } u; u.hh = h; return u.us;
}

// ---------- dtype detector: vote on exponent-byte signature of fp1_p2 ----------
__global__ void k_detect(const void* __restrict__ probe, int* __restrict__ flag) {
    if (threadIdx.x == 0 && blockIdx.x == 0) {
        const unsigned int* w = (const unsigned int*)probe;
        int hits = 0;
        for (int i = 0; i < 256; ++i) {
            unsigned int hb = (w[i] >> 8) & 0x7Fu;
            if (hb >= 0x3Bu && hb <= 0x40u) ++hits;
        }
        *flag = (hits >= 128) ? 1 : 0;               // 1 = bf16, 0 = fp32
    }
}

// ---------- weight transpose to fp32 (fp32 fallback path) ----------
__global__ void k_wt(const void* __restrict__ src, float* __restrict__ dst,
                     const int* __restrict__ dflag, int Eout, int Ein)
{
    int bf = *dflag;
    int idx = blockIdx.x * blockDim.x + threadIdx.x;
    int total = Eout * Ein;
    if (idx >= total) return;
    int e = idx / Ein, f = idx - e * Ein;
    dst[(size_t)f * Eout + e] = ldf(src, (size_t)idx, bf);
}

// ---------- combined bf16 weight prep: WcT[c][f], c in [0,3E), f in [0,2E) ----------
// cols: [0,E)=Q (f>=E zero-padded), [E,2E)=K, [2E,3E)=V
__global__ void k_wprep(const void* __restrict__ qw, const void* __restrict__ kw,
                        const void* __restrict__ vw, unsigned short* __restrict__ WcT,
                        const int* __restrict__ dflag, int E)
{
    int bf = *dflag;
    int idx = blockIdx.x * blockDim.x + threadIdx.x;
    int K2 = 2 * E;
    int total = 3 * E * K2;
    if (idx >= total) return;
    int c = idx / K2, f = idx - c * K2;
    float v;
    if (c < E)            v = (f < E) ? ldf(qw, (size_t)c * E + f, bf) : 0.f;
    else if (c < 2 * E)   v = ldf(kw, (size_t)(c - E) * K2 + f, bf);
    else                  v = ldf(vw, (size_t)(c - 2 * E) * K2 + f, bf);
    WcT[idx] = f2bf_bits(v);
}

// ---------- out-proj weight to bf16 (row-major [E][E], already W[c][f]=ow[c][f]) ----------
__global__ void k_woprep(const void* __restrict__ ow, unsigned short* __restrict__ WoT,
                         const int* __restrict__ dflag, int E)
{
    int bf = *dflag;
    int idx = blockIdx.x * blockDim.x + threadIdx.x;
    if (idx >= E * E) return;
    WoT[idx] = f2bf_bits(ldf(ow, (size_t)idx, bf));
}

// ---------- stitch index map ----------
__device__ __forceinline__ void stitch_map(int y, int x, int s, int nh, int nw,
                                           int& n, int& e)
{
    int px = x % s;
    int d0 = x / s;
    int M  = d0 * (nh * s) + y;
    int py = M / (nw * nh);
    int rem = M - py * (nw * nh);
    int iw = rem / nh;
    int ih = rem - iw * nh;
    n = ih * nw + iw;
    e = py * s + px;
}

// ---------- patchify (+ optional align-corners bilinear up-resize) ----------
__global__ void k_patchify(const void* __restrict__ fp1, const void* __restrict__ fp2,
                           float* __restrict__ qb, float* __restrict__ pb,
                           const int* __restrict__ dflag,
                           int bc0, int chunk, int N, int E, int s, int nh, int nw,
                           int h_, int w_, int h, int w, int resize)
{
    int bf = *dflag;
    int idx = blockIdx.x * blockDim.x + threadIdx.x;
    int total = chunk * N * E;
    if (idx >= total) return;
    int e = idx % E; int t = idx / E;
    int n = t % N;   int i = t / N;
    int ih = n / nw, iw = n - ih * nw;
    int py = e / s,  px = e - py * s;
    int Y = ih * s + py, X = iw * s + px;
    size_t base = (size_t)(bc0 + i) * h_ * w_;
    float v1, v2;
    if (!resize) {
        size_t off = base + (size_t)Y * w_ + X;
        v1 = ldf(fp1, off, bf); v2 = ldf(fp2, off, bf);
    } else {
        float fy = (float)Y * ((float)(h_ - 1) / (float)(h - 1));
        float fx = (float)X * ((float)(w_ - 1) / (float)(w - 1));
        int y0 = (int)floorf(fy); int x0 = (int)floorf(fx);
        float wy = fy - (float)y0, wx = fx - (float)x0;
        int y1 = min(y0 + 1, h_ - 1), x1 = min(x0 + 1, w_ - 1);
        size_t r0 = base + (size_t)y0 * w_, r1 = base + (size_t)y1 * w_;
        {
            float a00 = ldf(fp1, r0 + x0, bf), a01 = ldf(fp1, r0 + x1, bf);
            float a10 = ldf(fp1, r1 + x0, bf), a11 = ldf(fp1, r1 + x1, bf);
            v1 = (a00 * (1.f - wy) + a10 * wy) * (1.f - wx)
               + (a01 * (1.f - wy) + a11 * wy) * wx;
        }
        {
            float a00 = ldf(fp2, r0 + x0, bf), a01 = ldf(fp2, r0 + x1, bf);
            float a10 = ldf(fp2, r1 + x0, bf), a11 = ldf(fp2, r1 + x1, bf);
            v2 = (a00 * (1.f - wy) + a10 * wy) * (1.f - wx)
               + (a01 * (1.f - wy) + a11 * wy) * wx;
        }
    }
    qb[idx] = v1;
    pb[idx] = v2;
}

// ============================================================================
// MFMA GEMM (bf16 path only; early-exits on fp32).
// C[rows x Ncols] = concat(A1,A2)[rows x Ktot] @ W^T  + bias
//   A element k: k < Esplit -> A1[row*Esplit + k], else A2[row*(Ktot-Esplit)+(k-Esplit)]
//   W stored transposed: W[c*Ktot + k] (bf16 bits)
// mode 0: cols [0,E)->Q row-major, [E,2E)->Kt[(i*E+e)*N+n], [2E,3E)->V row-major
// mode 1: OUT row-major [rows x Ncols]
// Tile: 64x64, 4 waves (2x2 of 32x32), K-step 32 via mfma_f32_16x16x32_bf16.
// Operand layout (m156/m89): A lane l elem j: A[l&15][4*(l>>4)+j (+16 for j>=4)];
// B lane l: B[k same][l&15]; D lane l reg r: D[4*(l>>4)+r][l&15].
// ============================================================================
#define KPAD 40
__global__ __launch_bounds__(256) void
k_mgemm(const float* __restrict__ A1, const float* __restrict__ A2,
        const unsigned short* __restrict__ W, const void* __restrict__ bias,
        float* __restrict__ Q, float* __restrict__ Kt, float* __restrict__ V,
        float* __restrict__ OUT, const int* __restrict__ dflag,
        int rowsTot, int Ncols, int Ktot, int Esplit, int N, int E, int mode, int ctn)
{
    if (*dflag != 1) return;
    __shared__ __align__(16) unsigned char smem_raw[17472];
    unsigned short* sA = (unsigned short*)smem_raw;            // [64][KPAD]
    unsigned short* sB = sA + 64 * KPAD;                       // [64][KPAD]
    float* Ct = (float*)smem_raw;                              // [64][66] (epilogue)

    // bijective XCD-chunked swizzle (m204)
    int nwg = gridDim.x;
    int q8 = nwg >> 3, r8 = nwg & 7;
    int xcd = blockIdx.x & 7, bidx = blockIdx.x >> 3;
    int lin = (xcd < r8) ? (xcd * (q8 + 1) + bidx)
                         : (r8 * (q8 + 1) + (xcd - r8) * q8 + bidx);
    int rt = lin / ctn, ct = lin - rt * ctn;
    int row0 = rt * 64, cb0 = ct * 64;

    const int tid = threadIdx.x;
    const int sr = tid >> 2, seg = tid & 3;       // staging: row/col 0..63, k-seg 0..3
    const int lane = tid & 63, wid = tid >> 6;
    const int wr = wid >> 1, wc = wid & 1;
    const int lr = lane & 15;
    const int lk = (lane >> 4) << 2;              // 0,4,8,12

    float4v acc[2][2];
#pragma unroll
    for (int a = 0; a < 2; ++a)
#pragma unroll
        for (int b = 0; b < 2; ++b)
#pragma unroll
            for (int r = 0; r < 4; ++r) acc[a][b][r] = 0.f;

    const int nk = (Ktot + 31) >> 5;
    const int kfast = ((Ktot & 7) == 0);
    const size_t R = (size_t)row0 + sr;
    const bool rok = (row0 + sr) < rowsTot;
    const int strideA2 = Ktot - Esplit;

    for (int kt = 0; kt < nk; ++kt) {
        int k0 = kt << 5;
        // ---- stage A tile [64 rows][32 k] -> bf16 ----
        {
            int kb = k0 + seg * 8;
            float fv[8];
#pragma unroll
            for (int jj = 0; jj < 2; ++jj) {
                int ks = kb + jj * 4;
                float4 f;
                if (!rok) f = make_float4(0.f, 0.f, 0.f, 0.f);
                else if (ks + 3 < Esplit)
                    f = *(const float4*)(A1 + R * Esplit + ks);
                else if (ks >= Esplit && ks + 3 < Ktot)
                    f = *(const float4*)(A2 + R * (size_t)strideA2 + (ks - Esplit));
                else {
                    float t[4];
#pragma unroll
                    for (int q2 = 0; q2 < 4; ++q2) {
                        int k = ks + q2;
                        t[q2] = (k < Esplit) ? A1[R * Esplit + k]
                              : ((k < Ktot) ? A2[R * (size_t)strideA2 + (k - Esplit)] : 0.f);
                    }
                    f = make_float4(t[0], t[1], t[2], t[3]);
                }
                fv[jj*4+0] = f.x; fv[jj*4+1] = f.y; fv[jj*4+2] = f.z; fv[jj*4+3] = f.w;
            }
            union { uint4 u4; unsigned short us[8]; } pk;
#pragma unroll
            for (int q2 = 0; q2 < 8; ++q2) pk.us[q2] = f2bf_bits(fv[q2]);
            *(uint4*)&sA[sr * KPAD + seg * 8] = pk.u4;
        }
        // ---- stage B tile [64 cols][32 k] (already bf16) ----
        {
            int c = sr, kb = k0 + seg * 8;
            int gc = cb0 + c;
            if (gc < Ncols && kfast && (kb + 7) < Ktot) {
                *(uint4*)&sB[c * KPAD + seg * 8] = *(const uint4*)(W + (size_t)gc * Ktot + kb);
            } else {
#pragma unroll
                for (int q2 = 0; q2 < 8; ++q2) {
                    int k = kb + q2;
                    sB[c * KPAD + seg * 8 + q2] =
                        (gc < Ncols && k < Ktot) ? W[(size_t)gc * Ktot + k] : (unsigned short)0;
                }
            }
        }
        __syncthreads();
        // ---- fragments + MFMA ----
        union FragU { uint4 u4; short8v s; } fa[2], fb[2];
#pragma unroll
        for (int mr = 0; mr < 2; ++mr) {
            const unsigned short* base = &sA[(wr * 32 + mr * 16 + lr) * KPAD + lk];
            uint2 lo = *(const uint2*)base;
            uint2 hi = *(const uint2*)(base + 16);
            fa[mr].u4 = make_uint4(lo.x, lo.y, hi.x, hi.y);
        }
#pragma unroll
        for (int nc = 0; nc < 2; ++nc) {
            const unsigned short* base = &sB[(wc * 32 + nc * 16 + lr) * KPAD + lk];
            uint2 lo = *(const uint2*)base;
            uint2 hi = *(const uint2*)(base + 16);
            fb[nc].u4 = make_uint4(lo.x, lo.y, hi.x, hi.y);
        }
#pragma unroll
        for (int mr = 0; mr < 2; ++mr)
#pragma unroll
            for (int nc = 0; nc < 2; ++nc)
                acc[mr][nc] = __builtin_amdgcn_mfma_f32_16x16x32_bf16(
                    fa[mr].s, fb[nc].s, acc[mr][nc], 0, 0, 0);
        __syncthreads();
    }

    // ---- epilogue: bias, stage through LDS, routed stores ----
#pragma unroll
    for (int mr = 0; mr < 2; ++mr)
#pragma unroll
        for (int nc = 0; nc < 2; ++nc) {
            int cloc = wc * 32 + nc * 16 + lr;
            int gc = cb0 + cloc;
            float bv = (gc < Ncols) ? ldf(bias, (size_t)gc, 1) : 0.f;
#pragma unroll
            for (int r = 0; r < 4; ++r) {
                int rloc = wr * 32 + mr * 16 + ((lane >> 4) << 2) + r;
                Ct[rloc * 66 + cloc] = acc[mr][nc][r] + bv;
            }
        }
    __syncthreads();

    if (mode == 1) {
#pragma unroll
        for (int p = 0; p < 16; ++p) {
            int r = p * 4 + (tid >> 6);
            int cL = tid & 63;
            int gc = cb0 + cL;
            int gr = row0 + r;
            if (gr < rowsTot && gc < Ncols)
                OUT[(size_t)gr * Ncols + gc] = Ct[r * 66 + cL];
        }
    } else {
        // Q and V: row-major
#pragma unroll
        for (int p = 0; p < 16; ++p) {
            int r = p * 4 + (tid >> 6);
            int cL = tid & 63;
            int gc = cb0 + cL;
            int gr = row0 + r;
            if (gr < rowsTot && gc < Ncols) {
                float v = Ct[r * 66 + cL];
                if (gc < E)            Q[(size_t)gr * E + gc] = v;
                else if (gc >= 2 * E)  V[(size_t)gr * E + (gc - 2 * E)] = v;
            }
        }
        // K: transposed per item, coalesced along n
#pragma unroll
        for (int p = 0; p < 16; ++p) {
            int cL = p * 4 + (tid >> 6);
            int r = tid & 63;
            int gc = cb0 + cL;
            int gr = row0 + r;
            if (gr < rowsTot && gc >= E && gc < 2 * E) {
                int i = gr / N, n = gr - i * N;
                Kt[((size_t)i * E + (gc - E)) * N + n] = Ct[r * 66 + cL];
            }
        }
    }
}

// ---------- LayerNorm rows (bf16 path; wave per row) ----------
__global__ void k_ln(const float* __restrict__ X, float* __restrict__ Y,
                     const void* __restrict__ lng, const void* __restrict__ lnb,
                     const int* __restrict__ dflag, int rowsTot, int E)
{
    if (*dflag != 1) return;
    int lane = threadIdx.x & 63;
    int wpb = blockDim.x >> 6;
    int wid = (blockIdx.x * wpb) + (threadIdx.x >> 6);
    int nw = gridDim.x * wpb;
    for (int row = wid; row < rowsTot; row += nw) {
        const float* xr = X + (size_t)row * E;
        float s = 0.f, s2 = 0.f;
        for (int e = lane; e < E; e += 64) { float v = xr[e]; s += v; s2 += v * v; }
#pragma unroll
        for (int off = 32; off; off >>= 1) {
            s  += __shfl_xor(s, off);
            s2 += __shfl_xor(s2, off);
        }
        float mu  = s / (float)E;
        float var = s2 / (float)E - mu * mu;
        float inv = rsqrtf(var + 1e-5f);
        float* yr = Y + (size_t)row * E;
        for (int e = lane; e < E; e += 64) {
            float g = ldf(lng, e, 1), b = ldf(lnb, e, 1);
            yr[e] = (xr[e] - mu) * inv * g + b;
        }
    }
}

// ---------- fused Q,K,V projection, fp32 fallback ----------
template<int R>
__global__ void k_qkv2(const float* __restrict__ qb, const float* __restrict__ pb,
                       float* __restrict__ Q, float* __restrict__ Kt, float* __restrict__ V,
                       const float* __restrict__ qwT, const float* __restrict__ kwT,
                       const float* __restrict__ vwT, const void* __restrict__ inb,
                       const int* __restrict__ dflag, int N, int E)
{
    if (*dflag == 1) return;                  // bf16 handled by k_mgemm
    constexpr int RP = (R & 1) ? R : R + 1;
    int bf = 0;
    int e = threadIdx.x;
    long row0 = (long)blockIdx.x * R;
    int i  = (int)(row0 / N);
    int n0 = (int)(row0 - (long)i * N);
    extern __shared__ float sm[];
    float* sq = sm;
    float* sp = sm + (size_t)E * RP;
#pragma unroll
    for (int r = 0; r < R; ++r) {
        sq[(size_t)e * RP + r] = qb[(row0 + r) * (size_t)E + e];
        sp[(size_t)e * RP + r] = pb[(row0 + r) * (size_t)E + e];
    }
    __syncthreads();
    float aQ[R], aK[R], aV[R];
    float biQ = ldf(inb, e, bf), biK = ldf(inb, E + e, bf), biV = ldf(inb, 2 * E + e, bf);
#pragma unroll
    for (int r = 0; r < R; ++r) { aQ[r] = biQ; aK[r] = biK; aV[r] = biV; }
    const float* qwp = qwT + e;
    const float* kp1 = kwT + e;
    const float* kp2 = kwT + (size_t)E * E + e;
    const float* vp1 = vwT + e;
    const float* vp2 = vwT + (size_t)E * E + e;
#pragma unroll 2
    for (int f = 0; f < E; ++f) {
        float wq  = qwp[(size_t)f * E];
        float wk1 = kp1[(size_t)f * E];
        float wk2 = kp2[(size_t)f * E];
        float wv1 = vp1[(size_t)f * E];
        float wv2 = vp2[(size_t)f * E];
#pragma unroll
        for (int r = 0; r < R; ++r) {
            float qf = sq[(size_t)f * RP + r];
            float pf = sp[(size_t)f * RP + r];
            aQ[r] += qf * wq;
            aK[r] += qf * wk1 + pf * wk2;
            aV[r] += qf * wv1 + pf * wv2;
        }
    }
#pragma unroll
    for (int r = 0; r < R; ++r) {
        size_t o = (row0 + r) * (size_t)E + e;
        Q[o] = aQ[r]; V[o] = aV[r];
    }
    float* ktp = Kt + ((size_t)i * E + e) * N + n0;
    for (int r = 0; r < R; ++r) ktp[r] = aK[r];
}

// ---------- scores + softmax (dtype-independent: fp32 intermediates) ----------
template<int R>
__global__ void k_scores2(const float* __restrict__ Q, const float* __restrict__ Kt,
                          float* __restrict__ A, int N, int E, float scale)
{
    constexpr int RP = (R & 1) ? R : R + 1;
    int m = threadIdx.x;
    long row0 = (long)blockIdx.x * R;
    int i = (int)(row0 / N);
    extern __shared__ float sm[];
    float* sq   = sm;
    float* sred = sm + (size_t)E * RP;
    for (int r = 0; r < R; ++r)
        for (int e = m; e < E; e += N)
            sq[(size_t)e * RP + r] = Q[(row0 + r) * (size_t)E + e];
    __syncthreads();
    const float* Kb = Kt + (size_t)i * E * N + m;
    float acc[R];
#pragma unroll
    for (int r = 0; r < R; ++r) acc[r] = 0.f;
#pragma unroll 2
    for (int e = 0; e < E; ++e) {
        float kv = Kb[(size_t)e * N];
#pragma unroll
        for (int r = 0; r < R; ++r) acc[r] += sq[(size_t)e * RP + r] * kv;
    }
#pragma unroll
    for (int r = 0; r < R; ++r) acc[r] *= scale;
    for (int r = 0; r < R; ++r) {
        sred[m] = acc[r]; __syncthreads();
        for (int cnt = N; cnt > 1; ) {
            int half = (cnt + 1) >> 1;
            if (m < cnt - half) sred[m] = fmaxf(sred[m], sred[m + half]);
            __syncthreads();
            cnt = half;
        }
        float mx = sred[0]; __syncthreads();
        float ev = __expf(acc[r] - mx);
        sred[m] = ev; __syncthreads();
        for (int cnt = N; cnt > 1; ) {
            int half = (cnt + 1) >> 1;
            if (m < cnt - half) sred[m] += sred[m + half];
            __syncthreads();
            cnt = half;
        }
        float sum = sred[0]; __syncthreads();
        A[(row0 + r) * (size_t)N + m] = ev / sum;
    }
}

// ---------- O = A @ V ----------
template<int R>
__global__ void k_av(const float* __restrict__ A, const float* __restrict__ V,
                     float* __restrict__ O, int N, int E)
{
    constexpr int RP = (R & 1) ? R : R + 1;
    int e = threadIdx.x;
    long row0 = (long)blockIdx.x * R;
    int i = (int)(row0 / N);
    extern __shared__ float sm[];
    for (int r = 0; r < R; ++r)
        for (int m = e; m < N; m += E)
            sm[(size_t)m * RP + r] = A[(row0 + r) * (size_t)N + m];
    __syncthreads();
    const float* Vb = V + (size_t)i * N * E;
    float acc[R];
#pragma unroll
    for (int r = 0; r < R; ++r) acc[r] = 0.f;
#pragma unroll 2
    for (int m = 0; m < N; ++m) {
        float vv = Vb[(size_t)m * E + e];
#pragma unroll
        for (int r = 0; r < R; ++r) acc[r] += sm[(size_t)m * RP + r] * vv;
    }
#pragma unroll
    for (int r = 0; r < R; ++r) O[(row0 + r) * (size_t)E + e] = acc[r];
}

// ---------- out-proj + LayerNorm, fp32 fallback ----------
template<int R>
__global__ void k_projln2(const float* __restrict__ O, float* __restrict__ O2,
                          const float* __restrict__ owT, const void* __restrict__ ob,
                          const void* __restrict__ lng, const void* __restrict__ lnb,
                          const int* __restrict__ dflag, int E)
{
    if (*dflag == 1) return;                  // bf16 handled by k_mgemm+k_ln
    constexpr int RP = (R & 1) ? R : R + 1;
    int bf = 0;
    int e = threadIdx.x;
    long row0 = (long)blockIdx.x * R;
    extern __shared__ float sm[];
    float* so   = sm;
    float* sred = sm + (size_t)E * RP;
    for (int r = 0; r < R; ++r)
        so[(size_t)e * RP + r] = O[(row0 + r) * (size_t)E + e];
    __syncthreads();
    float acc[R];
    float bo = ldf(ob, e, bf);
#pragma unroll
    for (int r = 0; r < R; ++r) acc[r] = bo;
    const float* owp = owT + e;
#pragma unroll 2
    for (int f = 0; f < E; ++f) {
        float w = owp[(size_t)f * E];
#pragma unroll
        for (int r = 0; r < R; ++r) acc[r] += so[(size_t)f * RP + r] * w;
    }
    float g = ldf(lng, e, bf), bta = ldf(lnb, e, bf);
    for (int r = 0; r < R; ++r) {
        sred[e] = acc[r]; __syncthreads();
        for (int cnt = E; cnt > 1; ) {
            int half = (cnt + 1) >> 1;
            if (e < cnt - half) sred[e] += sred[e + half];
            __syncthreads();
            cnt = half;
        }
        float mu = sred[0] / (float)E; __syncthreads();
        float d = acc[r] - mu;
        sred[e] = d * d; __syncthreads();
        for (int cnt = E; cnt > 1; ) {
            int half = (cnt + 1) >> 1;
            if (e < cnt - half) sred[e] += sred[e + half];
            __syncthreads();
            cnt = half;
        }
        float var = sred[0] / (float)E; __syncthreads();
        O2[(row0 + r) * (size_t)E + e] = d * rsqrtf(var + 1e-5f) * g + bta;
    }
}

// ---------- final blend, no-resize levels ----------
__global__ void k_final(const float* __restrict__ O2,
                        const void* __restrict__ fp1, const void* __restrict__ fp2,
                        const void* __restrict__ logits, void* __restrict__ out,
                        const int* __restrict__ dflag, size_t obase,
                        int bc0, int chunk, int h, int w, int s, int nh, int nw,
                        int N, int E)
{
    int bf = *dflag;
    int idx = blockIdx.x * blockDim.x + threadIdx.x;
    int total = chunk * h * w;
    if (idx >= total) return;
    int x = idx % w; int t = idx / w;
    int y = t % h;   int i = t / h;
    int n, e;
    stitch_map(y, x, s, nh, nw, n, e);
    float fus = O2[((size_t)i * N + n) * E + e];
    float l0 = ldf(logits, 0, bf), l1 = ldf(logits, 1, bf), l2 = ldf(logits, 2, bf);
    float mx = fmaxf(l0, fmaxf(l1, l2));
    float e0 = __expf(l0 - mx), e1 = __expf(l1 - mx), e2 = __expf(l2 - mx);
    float inv = 1.f / (e0 + e1 + e2);
    size_t off = ((size_t)(bc0 + i) * h + y) * w + x;
    float v = ldf(fp1, off, bf) * (e0 * inv) + ldf(fp2, off, bf) * (e1 * inv)
            + fus * (e2 * inv);
    stf(out, obase + off, bf, v);
}

// ---------- stitch to full (rounded) grid, fp32 (p3 only) ----------
__global__ void k_stitch(const float* __restrict__ O2, float* __restrict__ st,
                         int chunk, int h, int w, int s, int nh, int nw, int N, int E)
{
    int idx = blockIdx.x * blockDim.x + threadIdx.x;
    int total = chunk * h * w;
    if (idx >= total) return;
    int x = idx % w; int t = idx / w;
    int y = t % h;   int i = t / h;
    int n, e;
    stitch_map(y, x, s, nh, nw, n, e);
    st[idx] = O2[((size_t)i * N + n) * E + e];
}

// ---------- down-resize (align corners) + blend (p3 only) ----------
__global__ void k_rblend(const float* __restrict__ st,
                         const void* __restrict__ fp1, const void* __restrict__ fp2,
                         const void* __restrict__ logits, void* __restrict__ out,
                         const int* __restrict__ dflag, size_t obase,
                         int bc0, int chunk, int h_, int w_, int h, int w)
{
    int bf = *dflag;
    int idx = blockIdx.x * blockDim.x + threadIdx.x;
    int total = chunk * h_ * w_;
    if (idx >= total) return;
    int x = idx % w_; int t = idx / w_;
    int y = t % h_;   int i = t / h_;
    float fy = (float)y * ((float)(h - 1) / (float)(h_ - 1));
    float fx = (float)x * ((float)(w - 1) / (float)(w_ - 1));
    int y0 = (int)floorf(fy); int x0 = (int)floorf(fx);
    float wy = fy - (float)y0, wx = fx - (float)x0;
    int y1 = min(y0 + 1, h - 1), x1 = min(x0 + 1, w - 1);
    size_t base = (size_t)i * h * w;
    float a00 = st[base + (size_t)y0 * w + x0], a01 = st[base + (size_t)y0 * w + x1];
    float a10 = st[base + (size_t)y1 * w + x0], a11 = st[base + (size_t)y1 * w + x1];
    float fus = (a00 * (1.f - wy) + a10 * wy) * (1.f - wx)
              + (a01 * (1.f - wy) + a11 * wy) * wx;
    float l0 = ldf(logits, 0, bf), l1 = ldf(logits, 1, bf), l2 = ldf(logits, 2, bf);
    float mx = fmaxf(l0, fmaxf(l1, l2));
    float e0 = __expf(l0 - mx), e1 = __expf(l1 - mx), e2 = __expf(l2 - mx);
    float inv = 1.f / (e0 + e1 + e2);
    size_t off = ((size_t)(bc0 + i) * h_ + y) * w_ + x;
    float v = ldf(fp1, off, bf) * (e0 * inv) + ldf(fp2, off, bf) * (e1 * inv)
            + fus * (e2 * inv);
    stf(out, obase + off, bf, v);
}

extern "C" void kernel_launch(void* const* d_in, const int* in_sizes, int n_in,
                              void* d_out, int out_size, void* d_ws, size_t ws_size,
                              hipStream_t stream)
{
    (void)in_sizes; (void)n_in; (void)out_size;
    const void* FP1[5]; const void* FP2[5];
    const void *QW[5], *KW[5], *VW[5], *INB[5], *OW[5], *OB[5], *LNG[5], *LNB[5];
    for (int l = 0; l < 5; ++l) {
        FP1[l] = d_in[l];
        FP2[l] = d_in[5 + l];
        int b = 10 + 8 * l;
        QW[l]  = d_in[b + 0];
        KW[l]  = d_in[b + 1];
        VW[l]  = d_in[b + 2];
        INB[l] = d_in[b + 3];
        OW[l]  = d_in[b + 4];
        OB[l]  = d_in[b + 5];
        LNG[l] = d_in[b + 6];
        LNB[l] = d_in[b + 7];
    }
    const void* logits = d_in[50];
    void* out = d_out;

    static const int HH[5] = {256, 128, 64, 32, 16};
    static const int SS[5] = {16, 12, 8, 4, 2};

    // ws layout: [6 fp32 slots][2.5MB weight region][dtype flag (16B)]
    size_t flag_off = (ws_size - 16) & ~(size_t)15;
    int* dflag = (int*)((char*)d_ws + flag_off);
    const size_t WRES = (size_t)2621440;   // 2.5MB: fp32 6E^2*4 + bf16 WcT + WoT at p2
    size_t wreg_off = (flag_off > WRES) ? ((flag_off - WRES) & ~(size_t)255) : 0;
    float* wreg = (float*)((char*)d_ws + wreg_off);
    size_t slot_bytes = (wreg_off / 6) & ~(size_t)255;
    size_t slot_elems = slot_bytes / sizeof(float);
    float* slot[6];
    for (int i = 0; i < 6; ++i) slot[i] = (float*)((char*)d_ws + (size_t)i * slot_bytes);

    k_detect<<<1, 64, 0, stream>>>(FP1[0], dflag);

    size_t ooff = 0;
    for (int l = 0; l < 5; ++l) {
        int h_ = HH[l], w_ = HH[l], s = SS[l];
        int nh = (h_ % s == 0) ? (h_ / s) : (h_ / s + 1);
        int nw = nh;
        int h = nh * s, w = nw * s;
        int N = nh * nw, E = s * s;
        int resize = (h != h_) ? 1 : 0;
        int Rq = (l == 1) ? 11 : 16;
        int Rr = (l == 1) ? 11 : 8;
        int RPq = (Rq & 1) ? Rq : Rq + 1;
        int RPr = (Rr & 1) ? Rr : Rr + 1;
        float scale = 1.0f / sqrtf((float)E);
        size_t maxNE = (size_t)N * (size_t)((E > N) ? E : N);

        // per-level weight prep
        float* wqT = wreg;
        float* wkT = wqT + (size_t)E * E;
        float* wvT = wkT + (size_t)2 * E * E;
        float* woT = wvT + (size_t)2 * E * E;
        unsigned short* WcT = (unsigned short*)(woT + (size_t)E * E);
        unsigned short* WoT = WcT + (size_t)3 * E * 2 * E;
        {
            int tpb = 256;
            k_wt<<<(E * E + tpb - 1) / tpb, tpb, 0, stream>>>(QW[l], wqT, dflag, E, E);
            k_wt<<<(2 * E * E + tpb - 1) / tpb, tpb, 0, stream>>>(KW[l], wkT, dflag, E, 2 * E);
            k_wt<<<(2 * E * E + tpb - 1) / tpb, tpb, 0, stream>>>(VW[l], wvT, dflag, E, 2 * E);
            k_wt<<<(E * E + tpb - 1) / tpb, tpb, 0, stream>>>(OW[l], woT, dflag, E, E);
            k_wprep<<<(3 * E * 2 * E + tpb - 1) / tpb, tpb, 0, stream>>>(QW[l], KW[l], VW[l], WcT, dflag, E);
            k_woprep<<<(E * E + tpb - 1) / tpb, tpb, 0, stream>>>(OW[l], WoT, dflag, E);
        }

        int chunk = 512;
        size_t c = (maxNE > 0) ? (slot_elems / maxNE) : 0;
        if (c < 512) { int p = 1; while ((size_t)(p << 1) <= c) p <<= 1; chunk = p; }
        int nchunks = 512 / chunk;

        for (int cidx = 0; cidx < nchunks; ++cidx) {
            int bc0 = cidx * chunk;
            int rows = chunk * N;
            int blocksQ = rows / Rq;
            int blocksR = rows / Rr;
            // 1) patchify
            {
                int tot = chunk * N * E, tpb = 256, g = (tot + tpb - 1) / tpb;
                k_patchify<<<g, tpb, 0, stream>>>(FP1[l], FP2[l], slot[0], slot[1],
                                                  dflag, bc0, chunk, N, E, s, nh, nw,
                                                  h_, w_, h, w, resize);
            }
            // 2) QKV: fp32 fallback (no-op when bf16)
            {
                size_t sh = (size_t)2 * RPq * E * sizeof(float);
                if (Rq == 16)
                    k_qkv2<16><<<blocksQ, E, sh, stream>>>(slot[0], slot[1], slot[2], slot[3], slot[4],
                                                           wqT, wkT, wvT, INB[l], dflag, N, E);
                else
                    k_qkv2<11><<<blocksQ, E, sh, stream>>>(slot[0], slot[1], slot[2], slot[3], slot[4],
                                                           wqT, wkT, wvT, INB[l], dflag, N, E);
            }
            // 2b) QKV: MFMA bf16 path (no-op when fp32)
            {
                int rt = (rows + 63) / 64, ctn = (3 * E + 63) / 64;
                k_mgemm<<<rt * ctn, 256, 0, stream>>>(slot[0], slot[1], WcT, INB[l],
                                                      slot[2], slot[3], slot[4], nullptr,
                                                      dflag, rows, 3 * E, 2 * E, E, N, E, 0, ctn);
            }
            // 3) scores + softmax
            {
                size_t sh = ((size_t)RPr * E + N) * sizeof(float);
                if (Rr == 8)
                    k_scores2<8><<<blocksR, N, sh, stream>>>(slot[2], slot[3], slot[5], N, E, scale);
                else
                    k_scores2<11><<<blocksR, N, sh, stream>>>(slot[2], slot[3], slot[5], N, E, scale);
            }
            // 4) O = A @ V
            {
                size_t sh = (size_t)RPr * N * sizeof(float);
                if (Rr == 8)
                    k_av<8><<<blocksR, E, sh, stream>>>(slot[5], slot[4], slot[0], N, E);
                else
                    k_av<11><<<blocksR, E, sh, stream>>>(slot[5], slot[4], slot[0], N, E);
            }
            // 5) out-proj + LN: fp32 fallback (no-op when bf16)
            {
                size_t sh = ((size_t)RPr * E + E) * sizeof(float);
                if (Rr == 8)
                    k_projln2<8><<<blocksR, E, sh, stream>>>(slot[0], slot[1], woT,
                                                             OB[l], LNG[l], LNB[l], dflag, E);
                else
                    k_projln2<11><<<blocksR, E, sh, stream>>>(slot[0], slot[1], woT,
                                                              OB[l], LNG[l], LNB[l], dflag, E);
            }
            // 5b) out-proj MFMA + LN (no-op when fp32)
            {
                int rt = (rows + 63) / 64, ctn = (E + 63) / 64;
                k_mgemm<<<rt * ctn, 256, 0, stream>>>(slot[0], slot[0], WoT, OB[l],
                                                      nullptr, nullptr, nullptr, slot[5],
                                                      dflag, rows, E, E, E, N, E, 1, ctn);
                int gb = (rows + 3) / 4; if (gb > 2048) gb = 2048;
                k_ln<<<gb, 256, 0, stream>>>(slot[5], slot[1], LNG[l], LNB[l], dflag, rows, E);
            }
            // 6) stitch (+resize) + blend
            if (!resize) {
                int tot = chunk * h * w, tpb = 256, g = (tot + tpb - 1) / tpb;
                k_final<<<g, tpb, 0, stream>>>(slot[1], FP1[l], FP2[l], logits, out,
                                               dflag, ooff, bc0, chunk, h, w, s, nh, nw, N, E);
            } else {
                int tot = chunk * h * w, tpb = 256, g = (tot + tpb - 1) / tpb;
                k_stitch<<<g, tpb, 0, stream>>>(slot[1], slot[2], chunk, h, w, s, nh, nw, N, E);
                int tot2 = chunk * h_ * w_, g2 = (tot2 + tpb - 1) / tpb;
                k_rblend<<<g2, tpb, 0, stream>>>(slot[2], FP1[l], FP2[l], logits, out,
                                                 dflag, ooff, bc0, chunk, h_, w_, h, w);
            }
        }
        ooff += (size_t)512 * h_ * w_;
    }
}

// Round 3
// 3484.136 us; speedup vs baseline: 8.3092x; 1.4849x over previous
//
#include <hip/hip_runtime.h>
#include <hip/hip_bf16.h>
#include <math.h>

typedef __hip_bfloat16 bf16;
typedef __attribute__((ext_vector_type(8))) short short8v;
typedef __attribute__((ext_vector_type(4))) float float4v;

// ---------- dtype-adaptive load/store (bf=1 -> bf16, bf=0 -> fp32) ----------
__device__ __forceinline__ float ldf(const void* p, size_t i, int bf) {
    if (bf) return __bfloat162float(((const bf16*)p)[i]);
    return ((const float*)p)[i];
}
__device__ __forceinline__ void stf(void* p, size_t i, int bf, float v) {
    if (bf) ((bf16*)p)[i] = __float2bfloat16(v);
    else    ((float*)p)[i] = v;
}
__device__ __forceinline__ unsigned short f2bf_bits(float x) {
    __hip_bfloat16 h = __float2bfloat16(x);
    union { __hip_bfloat16 hh; unsigned short us; } u; u.hh = h; return u.us;
}
__device__ __forceinline__ float bfbits2f(unsigned short h) {
    union { unsigned int u; float f; } t; t.u = ((unsigned int)h) << 16; return t.f;
}

// ---------- dtype detector: vote on exponent-byte signature of fp1_p2 ----------
__global__ void k_detect(const void* __restrict__ probe, int* __restrict__ flag) {
    if (threadIdx.x == 0 && blockIdx.x == 0) {
        const unsigned int* w = (const unsigned int*)probe;
        int hits = 0;
        for (int i = 0; i < 256; ++i) {
            unsigned int hb = (w[i] >> 8) & 0x7Fu;
            if (hb >= 0x3Bu && hb <= 0x40u) ++hits;
        }
        *flag = (hits >= 128) ? 1 : 0;               // 1 = bf16, 0 = fp32
    }
}

// ---------- combined QKV weight prep: hi/lo split-bf16, W[c][f], c in [0,3E) ----------
// cols: [0,E)=Q (f>=E zero-padded), [E,2E)=K, [2E,3E)=V. lo stored at offset total.
__global__ void k_wprep(const void* __restrict__ qw, const void* __restrict__ kw,
                        const void* __restrict__ vw, unsigned short* __restrict__ W,
                        const int* __restrict__ dflag, int E)
{
    int bf = *dflag;
    int idx = blockIdx.x * blockDim.x + threadIdx.x;
    int K2 = 2 * E;
    int total = 3 * E * K2;
    if (idx >= total) return;
    int c = idx / K2, f = idx - c * K2;
    float v;
    if (c < E)            v = (f < E) ? ldf(qw, (size_t)c * E + f, bf) : 0.f;
    else if (c < 2 * E)   v = ldf(kw, (size_t)(c - E) * K2 + f, bf);
    else                  v = ldf(vw, (size_t)(c - 2 * E) * K2 + f, bf);
    unsigned short h = f2bf_bits(v);
    W[idx] = h;
    W[(size_t)total + idx] = f2bf_bits(v - bfbits2f(h));
}

// ---------- out-proj weight prep: hi/lo split-bf16 [E][E] ----------
__global__ void k_woprep(const void* __restrict__ ow, unsigned short* __restrict__ W,
                         const int* __restrict__ dflag, int E)
{
    int bf = *dflag;
    int idx = blockIdx.x * blockDim.x + threadIdx.x;
    int total = E * E;
    if (idx >= total) return;
    float v = ldf(ow, (size_t)idx, bf);
    unsigned short h = f2bf_bits(v);
    W[idx] = h;
    W[(size_t)total + idx] = f2bf_bits(v - bfbits2f(h));
}

// ---------- stitch index map ----------
__device__ __forceinline__ void stitch_map(int y, int x, int s, int nh, int nw,
                                           int& n, int& e)
{
    int px = x % s;
    int d0 = x / s;
    int M  = d0 * (nh * s) + y;
    int py = M / (nw * nh);
    int rem = M - py * (nw * nh);
    int iw = rem / nh;
    int ih = rem - iw * nh;
    n = ih * nw + iw;
    e = py * s + px;
}

// ---------- patchify (+ optional align-corners bilinear up-resize) ----------
__global__ void k_patchify(const void* __restrict__ fp1, const void* __restrict__ fp2,
                           float* __restrict__ qb, float* __restrict__ pb,
                           const int* __restrict__ dflag,
                           int bc0, int chunk, int N, int E, int s, int nh, int nw,
                           int h_, int w_, int h, int w, int resize)
{
    int bf = *dflag;
    int idx = blockIdx.x * blockDim.x + threadIdx.x;
    int total = chunk * N * E;
    if (idx >= total) return;
    int e = idx % E; int t = idx / E;
    int n = t % N;   int i = t / N;
    int ih = n / nw, iw = n - ih * nw;
    int py = e / s,  px = e - py * s;
    int Y = ih * s + py, X = iw * s + px;
    size_t base = (size_t)(bc0 + i) * h_ * w_;
    float v1, v2;
    if (!resize) {
        size_t off = base + (size_t)Y * w_ + X;
        v1 = ldf(fp1, off, bf); v2 = ldf(fp2, off, bf);
    } else {
        float fy = (float)Y * ((float)(h_ - 1) / (float)(h - 1));
        float fx = (float)X * ((float)(w_ - 1) / (float)(w - 1));
        int y0 = (int)floorf(fy); int x0 = (int)floorf(fx);
        float wy = fy - (float)y0, wx = fx - (float)x0;
        int y1 = min(y0 + 1, h_ - 1), x1 = min(x0 + 1, w_ - 1);
        size_t r0 = base + (size_t)y0 * w_, r1 = base + (size_t)y1 * w_;
        {
            float a00 = ldf(fp1, r0 + x0, bf), a01 = ldf(fp1, r0 + x1, bf);
            float a10 = ldf(fp1, r1 + x0, bf), a11 = ldf(fp1, r1 + x1, bf);
            v1 = (a00 * (1.f - wy) + a10 * wy) * (1.f - wx)
               + (a01 * (1.f - wy) + a11 * wy) * wx;
        }
        {
            float a00 = ldf(fp2, r0 + x0, bf), a01 = ldf(fp2, r0 + x1, bf);
            float a10 = ldf(fp2, r1 + x0, bf), a11 = ldf(fp2, r1 + x1, bf);
            v2 = (a00 * (1.f - wy) + a10 * wy) * (1.f - wx)
               + (a01 * (1.f - wy) + a11 * wy) * wx;
        }
    }
    qb[idx] = v1;
    pb[idx] = v2;
}

// ============================================================================
// Split-bf16 MFMA GEMM (works for BOTH input dtypes; A is fp32 workspace).
// C[rows x Ncols] = concat(A1,A2)[rows x Ktot] @ W^T + bias, where each fp32
// value x = hi + lo (bf16 split, exact in fp32) and x*w is computed via
// 3 MFMAs: hi*hi + hi*lo + lo*hi (fp32 accumulate). Effective rel.err ~2^-16.
// W: prepped bf16 hi at W[c*Ktot+k], lo at W[Ncols*Ktot + c*Ktot+k].
// mode 0: cols [0,E)->Q row-major, [E,2E)->Kt[(i*E+e)*N+n], [2E,3E)->V row-major
// mode 1: OUT row-major [rows x Ncols]
// Tile 64x64, 4 waves (2x2 of 32x32), K-step 32 via mfma_f32_16x16x32_bf16.
// Fragment layout (m156/m89): A lane l elem j -> A[l&15][4*(l>>4)+j (+16, j>=4)];
// B symmetric; D lane l reg r -> D[4*(l>>4)+r][l&15].
// ============================================================================
#define KPAD 40
__global__ __launch_bounds__(256) void
k_mgemm(const float* __restrict__ A1, const float* __restrict__ A2,
        const unsigned short* __restrict__ W, const void* __restrict__ bias,
        float* __restrict__ Q, float* __restrict__ Kt, float* __restrict__ V,
        float* __restrict__ OUT, const int* __restrict__ dflag,
        int rowsTot, int Ncols, int Ktot, int Esplit, int N, int E, int mode, int ctn)
{
    const int bf = *dflag;
    __shared__ __align__(16) unsigned char smem_raw[20480];
    unsigned short* sAh = (unsigned short*)smem_raw;           // [64][KPAD]
    unsigned short* sAl = sAh + 64 * KPAD;
    unsigned short* sBh = sAl + 64 * KPAD;
    unsigned short* sBl = sBh + 64 * KPAD;
    float* Ct = (float*)smem_raw;                              // [64][66] (epilogue)

    // bijective XCD-chunked swizzle (m204)
    int nwg = gridDim.x;
    int q8 = nwg >> 3, r8 = nwg & 7;
    int xcd = blockIdx.x & 7, bidx = blockIdx.x >> 3;
    int lin = (xcd < r8) ? (xcd * (q8 + 1) + bidx)
                         : (r8 * (q8 + 1) + (xcd - r8) * q8 + bidx);
    int rt = lin / ctn, ct = lin - rt * ctn;
    int row0 = rt * 64, cb0 = ct * 64;

    const int tid = threadIdx.x;
    const int sr = tid >> 2, seg = tid & 3;       // staging: row/col 0..63, k-seg 0..3
    const int lane = tid & 63;
    const int wid = tid >> 6;
    const int wr = wid >> 1, wc = wid & 1;
    const int lr = lane & 15;
    const int lk = (lane >> 4) << 2;              // 0,4,8,12

    float4v acc[2][2];
#pragma unroll
    for (int a = 0; a < 2; ++a)
#pragma unroll
        for (int b = 0; b < 2; ++b)
#pragma unroll
            for (int r = 0; r < 4; ++r) acc[a][b][r] = 0.f;

    const int nk = (Ktot + 31) >> 5;
    const int kfast = ((Ktot & 7) == 0);
    const size_t R = (size_t)row0 + sr;
    const bool rok = (row0 + sr) < rowsTot;
    const int strideA2 = Ktot - Esplit;
    const unsigned short* Wl = W + (size_t)Ncols * Ktot;

    for (int kt = 0; kt < nk; ++kt) {
        int k0 = kt << 5;
        // ---- stage A tile [64 rows][32 k]: fp32 -> hi/lo bf16 ----
        {
            int kb = k0 + seg * 8;
            float fv[8];
#pragma unroll
            for (int jj = 0; jj < 2; ++jj) {
                int ks = kb + jj * 4;
                float4 f;
                if (!rok) f = make_float4(0.f, 0.f, 0.f, 0.f);
                else if (ks + 3 < Esplit)
                    f = *(const float4*)(A1 + R * Esplit + ks);
                else if (ks >= Esplit && ks + 3 < Ktot)
                    f = *(const float4*)(A2 + R * (size_t)strideA2 + (ks - Esplit));
                else {
                    float t[4];
#pragma unroll
                    for (int q2 = 0; q2 < 4; ++q2) {
                        int k = ks + q2;
                        t[q2] = (k < Esplit) ? A1[R * Esplit + k]
                              : ((k < Ktot) ? A2[R * (size_t)strideA2 + (k - Esplit)] : 0.f);
                    }
                    f = make_float4(t[0], t[1], t[2], t[3]);
                }
                fv[jj*4+0] = f.x; fv[jj*4+1] = f.y; fv[jj*4+2] = f.z; fv[jj*4+3] = f.w;
            }
            union { uint4 u4; unsigned short us[8]; } ph, pl;
#pragma unroll
            for (int q2 = 0; q2 < 8; ++q2) {
                unsigned short hb = f2bf_bits(fv[q2]);
                ph.us[q2] = hb;
                pl.us[q2] = f2bf_bits(fv[q2] - bfbits2f(hb));
            }
            *(uint4*)&sAh[sr * KPAD + seg * 8] = ph.u4;
            *(uint4*)&sAl[sr * KPAD + seg * 8] = pl.u4;
        }
        // ---- stage B tile [64 cols][32 k] from prepped hi/lo ----
        {
            int c = sr, kb = k0 + seg * 8;
            int gc = cb0 + c;
            if (gc < Ncols && kfast && (kb + 7) < Ktot) {
                *(uint4*)&sBh[c * KPAD + seg * 8] = *(const uint4*)(W  + (size_t)gc * Ktot + kb);
                *(uint4*)&sBl[c * KPAD + seg * 8] = *(const uint4*)(Wl + (size_t)gc * Ktot + kb);
            } else {
#pragma unroll
                for (int q2 = 0; q2 < 8; ++q2) {
                    int k = kb + q2;
                    bool ok = (gc < Ncols && k < Ktot);
                    sBh[c * KPAD + seg * 8 + q2] = ok ? W [(size_t)gc * Ktot + k] : (unsigned short)0;
                    sBl[c * KPAD + seg * 8 + q2] = ok ? Wl[(size_t)gc * Ktot + k] : (unsigned short)0;
                }
            }
        }
        __syncthreads();
        // ---- fragments + 3-MFMA emulated fp32 product ----
        union FragU { uint4 u4; short8v s; } fah[2], fal[2], fbh[2], fbl[2];
#pragma unroll
        for (int mr = 0; mr < 2; ++mr) {
            const unsigned short* bh = &sAh[(wr * 32 + mr * 16 + lr) * KPAD + lk];
            uint2 lo = *(const uint2*)bh;  uint2 hi = *(const uint2*)(bh + 16);
            fah[mr].u4 = make_uint4(lo.x, lo.y, hi.x, hi.y);
            const unsigned short* bl = &sAl[(wr * 32 + mr * 16 + lr) * KPAD + lk];
            uint2 lo2 = *(const uint2*)bl; uint2 hi2 = *(const uint2*)(bl + 16);
            fal[mr].u4 = make_uint4(lo2.x, lo2.y, hi2.x, hi2.y);
        }
#pragma unroll
        for (int nc = 0; nc < 2; ++nc) {
            const unsigned short* bh = &sBh[(wc * 32 + nc * 16 + lr) * KPAD + lk];
            uint2 lo = *(const uint2*)bh;  uint2 hi = *(const uint2*)(bh + 16);
            fbh[nc].u4 = make_uint4(lo.x, lo.y, hi.x, hi.y);
            const unsigned short* bl = &sBl[(wc * 32 + nc * 16 + lr) * KPAD + lk];
            uint2 lo2 = *(const uint2*)bl; uint2 hi2 = *(const uint2*)(bl + 16);
            fbl[nc].u4 = make_uint4(lo2.x, lo2.y, hi2.x, hi2.y);
        }
#pragma unroll
        for (int mr = 0; mr < 2; ++mr)
#pragma unroll
            for (int nc = 0; nc < 2; ++nc) {
                acc[mr][nc] = __builtin_amdgcn_mfma_f32_16x16x32_bf16(
                    fah[mr].s, fbl[nc].s, acc[mr][nc], 0, 0, 0);
                acc[mr][nc] = __builtin_amdgcn_mfma_f32_16x16x32_bf16(
                    fal[mr].s, fbh[nc].s, acc[mr][nc], 0, 0, 0);
                acc[mr][nc] = __builtin_amdgcn_mfma_f32_16x16x32_bf16(
                    fah[mr].s, fbh[nc].s, acc[mr][nc], 0, 0, 0);
            }
        __syncthreads();
    }

    // ---- epilogue: bias, stage through LDS, routed stores ----
#pragma unroll
    for (int mr = 0; mr < 2; ++mr)
#pragma unroll
        for (int nc = 0; nc < 2; ++nc) {
            int cloc = wc * 32 + nc * 16 + lr;
            int gc = cb0 + cloc;
            float bv = (gc < Ncols) ? ldf(bias, (size_t)gc, bf) : 0.f;
#pragma unroll
            for (int r = 0; r < 4; ++r) {
                int rloc = wr * 32 + mr * 16 + ((lane >> 4) << 2) + r;
                Ct[rloc * 66 + cloc] = acc[mr][nc][r] + bv;
            }
        }
    __syncthreads();

    if (mode == 1) {
#pragma unroll
        for (int p = 0; p < 16; ++p) {
            int r = p * 4 + (tid >> 6);
            int cL = tid & 63;
            int gc = cb0 + cL;
            int gr = row0 + r;
            if (gr < rowsTot && gc < Ncols)
                OUT[(size_t)gr * Ncols + gc] = Ct[r * 66 + cL];
        }
    } else {
        // Q and V: row-major
#pragma unroll
        for (int p = 0; p < 16; ++p) {
            int r = p * 4 + (tid >> 6);
            int cL = tid & 63;
            int gc = cb0 + cL;
            int gr = row0 + r;
            if (gr < rowsTot && gc < Ncols) {
                float v = Ct[r * 66 + cL];
                if (gc < E)            Q[(size_t)gr * E + gc] = v;
                else if (gc >= 2 * E)  V[(size_t)gr * E + (gc - 2 * E)] = v;
            }
        }
        // K: transposed per item, coalesced along n
#pragma unroll
        for (int p = 0; p < 16; ++p) {
            int cL = p * 4 + (tid >> 6);
            int r = tid & 63;
            int gc = cb0 + cL;
            int gr = row0 + r;
            if (gr < rowsTot && gc >= E && gc < 2 * E) {
                int i = gr / N, n = gr - i * N;
                Kt[((size_t)i * E + (gc - E)) * N + n] = Ct[r * 66 + cL];
            }
        }
    }
}

// ---------- LayerNorm rows (wave per row) ----------
__global__ void k_ln(const float* __restrict__ X, float* __restrict__ Y,
                     const void* __restrict__ lng, const void* __restrict__ lnb,
                     const int* __restrict__ dflag, int rowsTot, int E)
{
    int bf = *dflag;
    int lane = threadIdx.x & 63;
    int wpb = blockDim.x >> 6;
    int wid = (blockIdx.x * wpb) + (threadIdx.x >> 6);
    int nw = gridDim.x * wpb;
    for (int row = wid; row < rowsTot; row += nw) {
        const float* xr = X + (size_t)row * E;
        float s = 0.f, s2 = 0.f;
        for (int e = lane; e < E; e += 64) { float v = xr[e]; s += v; s2 += v * v; }
#pragma unroll
        for (int off = 32; off; off >>= 1) {
            s  += __shfl_xor(s, off);
            s2 += __shfl_xor(s2, off);
        }
        float mu  = s / (float)E;
        float var = s2 / (float)E - mu * mu;
        float inv = rsqrtf(var + 1e-5f);
        float* yr = Y + (size_t)row * E;
        for (int e = lane; e < E; e += 64) {
            float g = ldf(lng, e, bf), b = ldf(lnb, e, bf);
            yr[e] = (xr[e] - mu) * inv * g + b;
        }
    }
}

// ---------- scores + softmax (fp32 intermediates) ----------
template<int R>
__global__ void k_scores2(const float* __restrict__ Q, const float* __restrict__ Kt,
                          float* __restrict__ A, int N, int E, float scale)
{
    constexpr int RP = (R & 1) ? R : R + 1;
    int m = threadIdx.x;
    long row0 = (long)blockIdx.x * R;
    int i = (int)(row0 / N);
    extern __shared__ float sm[];
    float* sq   = sm;
    float* sred = sm + (size_t)E * RP;
    for (int r = 0; r < R; ++r)
        for (int e = m; e < E; e += N)
            sq[(size_t)e * RP + r] = Q[(row0 + r) * (size_t)E + e];
    __syncthreads();
    const float* Kb = Kt + (size_t)i * E * N + m;
    float acc[R];
#pragma unroll
    for (int r = 0; r < R; ++r) acc[r] = 0.f;
#pragma unroll 2
    for (int e = 0; e < E; ++e) {
        float kv = Kb[(size_t)e * N];
#pragma unroll
        for (int r = 0; r < R; ++r) acc[r] += sq[(size_t)e * RP + r] * kv;
    }
#pragma unroll
    for (int r = 0; r < R; ++r) acc[r] *= scale;
    for (int r = 0; r < R; ++r) {
        sred[m] = acc[r]; __syncthreads();
        for (int cnt = N; cnt > 1; ) {
            int half = (cnt + 1) >> 1;
            if (m < cnt - half) sred[m] = fmaxf(sred[m], sred[m + half]);
            __syncthreads();
            cnt = half;
        }
        float mx = sred[0]; __syncthreads();
        float ev = __expf(acc[r] - mx);
        sred[m] = ev; __syncthreads();
        for (int cnt = N; cnt > 1; ) {
            int half = (cnt + 1) >> 1;
            if (m < cnt - half) sred[m] += sred[m + half];
            __syncthreads();
            cnt = half;
        }
        float sum = sred[0]; __syncthreads();
        A[(row0 + r) * (size_t)N + m] = ev / sum;
    }
}

// ---------- O = A @ V ----------
template<int R>
__global__ void k_av(const float* __restrict__ A, const float* __restrict__ V,
                     float* __restrict__ O, int N, int E)
{
    constexpr int RP = (R & 1) ? R : R + 1;
    int e = threadIdx.x;
    long row0 = (long)blockIdx.x * R;
    int i = (int)(row0 / N);
    extern __shared__ float sm[];
    for (int r = 0; r < R; ++r)
        for (int m = e; m < N; m += E)
            sm[(size_t)m * RP + r] = A[(row0 + r) * (size_t)N + m];
    __syncthreads();
    const float* Vb = V + (size_t)i * N * E;
    float acc[R];
#pragma unroll
    for (int r = 0; r < R; ++r) acc[r] = 0.f;
#pragma unroll 2
    for (int m = 0; m < N; ++m) {
        float vv = Vb[(size_t)m * E + e];
#pragma unroll
        for (int r = 0; r < R; ++r) acc[r] += sm[(size_t)m * RP + r] * vv;
    }
#pragma unroll
    for (int r = 0; r < R; ++r) O[(row0 + r) * (size_t)E + e] = acc[r];
}

// ---------- final blend, no-resize levels ----------
__global__ void k_final(const float* __restrict__ O2,
                        const void* __restrict__ fp1, const void* __restrict__ fp2,
                        const void* __restrict__ logits, void* __restrict__ out,
                        const int* __restrict__ dflag, size_t obase,
                        int bc0, int chunk, int h, int w, int s, int nh, int nw,
                        int N, int E)
{
    int bf = *dflag;
    int idx = blockIdx.x * blockDim.x + threadIdx.x;
    int total = chunk * h * w;
    if (idx >= total) return;
    int x = idx % w; int t = idx / w;
    int y = t % h;   int i = t / h;
    int n, e;
    stitch_map(y, x, s, nh, nw, n, e);
    float fus = O2[((size_t)i * N + n) * E + e];
    float l0 = ldf(logits, 0, bf), l1 = ldf(logits, 1, bf), l2 = ldf(logits, 2, bf);
    float mx = fmaxf(l0, fmaxf(l1, l2));
    float e0 = __expf(l0 - mx), e1 = __expf(l1 - mx), e2 = __expf(l2 - mx);
    float inv = 1.f / (e0 + e1 + e2);
    size_t off = ((size_t)(bc0 + i) * h + y) * w + x;
    float v = ldf(fp1, off, bf) * (e0 * inv) + ldf(fp2, off, bf) * (e1 * inv)
            + fus * (e2 * inv);
    stf(out, obase + off, bf, v);
}

// ---------- stitch to full (rounded) grid, fp32 (p3 only) ----------
__global__ void k_stitch(const float* __restrict__ O2, float* __restrict__ st,
                         int chunk, int h, int w, int s, int nh, int nw, int N, int E)
{
    int idx = blockIdx.x * blockDim.x + threadIdx.x;
    int total = chunk * h * w;
    if (idx >= total) return;
    int x = idx % w; int t = idx / w;
    int y = t % h;   int i = t / h;
    int n, e;
    stitch_map(y, x, s, nh, nw, n, e);
    st[idx] = O2[((size_t)i * N + n) * E + e];
}

// ---------- down-resize (align corners) + blend (p3 only) ----------
__global__ void k_rblend(const float* __restrict__ st,
                         const void* __restrict__ fp1, const void* __restrict__ fp2,
                         const void* __restrict__ logits, void* __restrict__ out,
                         const int* __restrict__ dflag, size_t obase,
                         int bc0, int chunk, int h_, int w_, int h, int w)
{
    int bf = *dflag;
    int idx = blockIdx.x * blockDim.x + threadIdx.x;
    int total = chunk * h_ * w_;
    if (idx >= total) return;
    int x = idx % w_; int t = idx / w_;
    int y = t % h_;   int i = t / h_;
    float fy = (float)y * ((float)(h - 1) / (float)(h_ - 1));
    float fx = (float)x * ((float)(w - 1) / (float)(w_ - 1));
    int y0 = (int)floorf(fy); int x0 = (int)floorf(fx);
    float wy = fy - (float)y0, wx = fx - (float)x0;
    int y1 = min(y0 + 1, h - 1), x1 = min(x0 + 1, w - 1);
    size_t base = (size_t)i * h * w;
    float a00 = st[base + (size_t)y0 * w + x0], a01 = st[base + (size_t)y0 * w + x1];
    float a10 = st[base + (size_t)y1 * w + x0], a11 = st[base + (size_t)y1 * w + x1];
    float fus = (a00 * (1.f - wy) + a10 * wy) * (1.f - wx)
              + (a01 * (1.f - wy) + a11 * wy) * wx;
    float l0 = ldf(logits, 0, bf), l1 = ldf(logits, 1, bf), l2 = ldf(logits, 2, bf);
    float mx = fmaxf(l0, fmaxf(l1, l2));
    float e0 = __expf(l0 - mx), e1 = __expf(l1 - mx), e2 = __expf(l2 - mx);
    float inv = 1.f / (e0 + e1 + e2);
    size_t off = ((size_t)(bc0 + i) * h_ + y) * w_ + x;
    float v = ldf(fp1, off, bf) * (e0 * inv) + ldf(fp2, off, bf) * (e1 * inv)
            + fus * (e2 * inv);
    stf(out, obase + off, bf, v);
}

extern "C" void kernel_launch(void* const* d_in, const int* in_sizes, int n_in,
                              void* d_out, int out_size, void* d_ws, size_t ws_size,
                              hipStream_t stream)
{
    (void)in_sizes; (void)n_in; (void)out_size;
    const void* FP1[5]; const void* FP2[5];
    const void *QW[5], *KW[5], *VW[5], *INB[5], *OW[5], *OB[5], *LNG[5], *LNB[5];
    for (int l = 0; l < 5; ++l) {
        FP1[l] = d_in[l];
        FP2[l] = d_in[5 + l];
        int b = 10 + 8 * l;
        QW[l]  = d_in[b + 0];
        KW[l]  = d_in[b + 1];
        VW[l]  = d_in[b + 2];
        INB[l] = d_in[b + 3];
        OW[l]  = d_in[b + 4];
        OB[l]  = d_in[b + 5];
        LNG[l] = d_in[b + 6];
        LNB[l] = d_in[b + 7];
    }
    const void* logits = d_in[50];
    void* out = d_out;

    static const int HH[5] = {256, 128, 64, 32, 16};
    static const int SS[5] = {16, 12, 8, 4, 2};

    // ws layout: [6 fp32 slots][2.5MB weight region][dtype flag (16B)]
    size_t flag_off = (ws_size - 16) & ~(size_t)15;
    int* dflag = (int*)((char*)d_ws + flag_off);
    const size_t WRES = (size_t)2621440;   // 2.5MB: hi/lo WcP (1.57MB) + WoP (0.26MB) at p2
    size_t wreg_off = (flag_off > WRES) ? ((flag_off - WRES) & ~(size_t)255) : 0;
    size_t slot_bytes = (wreg_off / 6) & ~(size_t)255;
    size_t slot_elems = slot_bytes / sizeof(float);
    float* slot[6];
    for (int i = 0; i < 6; ++i) slot[i] = (float*)((char*)d_ws + (size_t)i * slot_bytes);

    k_detect<<<1, 64, 0, stream>>>(FP1[0], dflag);

    size_t ooff = 0;
    for (int l = 0; l < 5; ++l) {
        int h_ = HH[l], w_ = HH[l], s = SS[l];
        int nh = (h_ % s == 0) ? (h_ / s) : (h_ / s + 1);
        int nw = nh;
        int h = nh * s, w = nw * s;
        int N = nh * nw, E = s * s;
        int resize = (h != h_) ? 1 : 0;
        int Rr = (l == 1) ? 11 : 8;     // scores/av rows per block (divides N)
        float scale = 1.0f / sqrtf((float)E);
        size_t maxNE = (size_t)N * (size_t)((E > N) ? E : N);

        // per-level weight prep: hi/lo split-bf16
        unsigned short* WcP = (unsigned short*)((char*)d_ws + wreg_off);
        unsigned short* WoP = WcP + (size_t)2 * 3 * E * 2 * E;
        {
            int tpb = 256;
            k_wprep<<<(3 * E * 2 * E + tpb - 1) / tpb, tpb, 0, stream>>>(QW[l], KW[l], VW[l], WcP, dflag, E);
            k_woprep<<<(E * E + tpb - 1) / tpb, tpb, 0, stream>>>(OW[l], WoP, dflag, E);
        }

        int chunk = 512;
        size_t c = (maxNE > 0) ? (slot_elems / maxNE) : 0;
        if (c < 512) { int p = 1; while ((size_t)(p << 1) <= c) p <<= 1; chunk = p; }
        int nchunks = 512 / chunk;

        for (int cidx = 0; cidx < nchunks; ++cidx) {
            int bc0 = cidx * chunk;
            int rows = chunk * N;
            int blocksR = rows / Rr;
            // 1) patchify
            {
                int tot = chunk * N * E, tpb = 256, g = (tot + tpb - 1) / tpb;
                k_patchify<<<g, tpb, 0, stream>>>(FP1[l], FP2[l], slot[0], slot[1],
                                                  dflag, bc0, chunk, N, E, s, nh, nw,
                                                  h_, w_, h, w, resize);
            }
            // 2) QKV via split-bf16 MFMA
            {
                int rt = (rows + 63) / 64, ctn = (3 * E + 63) / 64;
                k_mgemm<<<rt * ctn, 256, 0, stream>>>(slot[0], slot[1], WcP, INB[l],
                                                      slot[2], slot[3], slot[4], nullptr,
                                                      dflag, rows, 3 * E, 2 * E, E, N, E, 0, ctn);
            }
            // 3) scores + softmax
            {
                int RPr = (Rr & 1) ? Rr : Rr + 1;
                size_t sh = ((size_t)RPr * E + N) * sizeof(float);
                if (Rr == 8)
                    k_scores2<8><<<blocksR, N, sh, stream>>>(slot[2], slot[3], slot[5], N, E, scale);
                else
                    k_scores2<11><<<blocksR, N, sh, stream>>>(slot[2], slot[3], slot[5], N, E, scale);
            }
            // 4) O = A @ V
            {
                int RPr = (Rr & 1) ? Rr : Rr + 1;
                size_t sh = (size_t)RPr * N * sizeof(float);
                if (Rr == 8)
                    k_av<8><<<blocksR, E, sh, stream>>>(slot[5], slot[4], slot[0], N, E);
                else
                    k_av<11><<<blocksR, E, sh, stream>>>(slot[5], slot[4], slot[0], N, E);
            }
            // 5) out-proj via split-bf16 MFMA, then LN
            {
                int rt = (rows + 63) / 64, ctn = (E + 63) / 64;
                k_mgemm<<<rt * ctn, 256, 0, stream>>>(slot[0], slot[0], WoP, OB[l],
                                                      nullptr, nullptr, nullptr, slot[5],
                                                      dflag, rows, E, E, E, N, E, 1, ctn);
                int gb = (rows + 3) / 4; if (gb > 2048) gb = 2048;
                k_ln<<<gb, 256, 0, stream>>>(slot[5], slot[1], LNG[l], LNB[l], dflag, rows, E);
            }
            // 6) stitch (+resize) + blend
            if (!resize) {
                int tot = chunk * h * w, tpb = 256, g = (tot + tpb - 1) / tpb;
                k_final<<<g, tpb, 0, stream>>>(slot[1], FP1[l], FP2[l], logits, out,
                                               dflag, ooff, bc0, chunk, h, w, s, nh, nw, N, E);
            } else {
                int tot = chunk * h * w, tpb = 256, g = (tot + tpb - 1) / tpb;
                k_stitch<<<g, tpb, 0, stream>>>(slot[1], slot[2], chunk, h, w, s, nh, nw, N, E);
                int tot2 = chunk * h_ * w_, g2 = (tot2 + tpb - 1) / tpb;
                k_rblend<<<g2, tpb, 0, stream>>>(slot[2], FP1[l], FP2[l], logits, out,
                                                 dflag, ooff, bc0, chunk, h_, w_, h, w);
            }
        }
        ooff += (size_t)512 * h_ * w_;
    }
}

// Round 5
// 2309.826 us; speedup vs baseline: 12.5335x; 1.5084x over previous
//
#include <hip/hip_runtime.h>
#include <hip/hip_bf16.h>
#include <math.h>

typedef __hip_bfloat16 bf16;
typedef __attribute__((ext_vector_type(8))) short short8v;
typedef __attribute__((ext_vector_type(4))) float float4v;

// ---------- dtype-adaptive load/store (bf=1 -> bf16, bf=0 -> fp32) ----------
__device__ __forceinline__ float ldf(const void* p, size_t i, int bf) {
    if (bf) return __bfloat162float(((const bf16*)p)[i]);
    return ((const float*)p)[i];
}
__device__ __forceinline__ void stf(void* p, size_t i, int bf, float v) {
    if (bf) ((bf16*)p)[i] = __float2bfloat16(v);
    else    ((float*)p)[i] = v;
}
__device__ __forceinline__ unsigned short f2bf_bits(float x) {
    __hip_bfloat16 h = __float2bfloat16(x);
    union { __hip_bfloat16 hh; unsigned short us; } u; u.hh = h; return u.us;
}
__device__ __forceinline__ float bfbits2f(unsigned short h) {
    union { unsigned int u; float f; } t; t.u = ((unsigned int)h) << 16; return t.f;
}

// ---------- dtype detector ----------
__global__ void k_detect(const void* __restrict__ probe, int* __restrict__ flag) {
    if (threadIdx.x == 0 && blockIdx.x == 0) {
        const unsigned int* w = (const unsigned int*)probe;
        int hits = 0;
        for (int i = 0; i < 256; ++i) {
            unsigned int hb = (w[i] >> 8) & 0x7Fu;
            if (hb >= 0x3Bu && hb <= 0x40u) ++hits;
        }
        *flag = (hits >= 128) ? 1 : 0;               // 1 = bf16, 0 = fp32
    }
}

// ---------- combined QKV weight prep: hi/lo split-bf16, W[c][f], c in [0,3E) ----------
__global__ void k_wprep(const void* __restrict__ qw, const void* __restrict__ kw,
                        const void* __restrict__ vw, unsigned short* __restrict__ W,
                        const int* __restrict__ dflag, int E)
{
    int bf = *dflag;
    int idx = blockIdx.x * blockDim.x + threadIdx.x;
    int K2 = 2 * E;
    int total = 3 * E * K2;
    if (idx >= total) return;
    int c = idx / K2, f = idx - c * K2;
    float v;
    if (c < E)            v = (f < E) ? ldf(qw, (size_t)c * E + f, bf) : 0.f;
    else if (c < 2 * E)   v = ldf(kw, (size_t)(c - E) * K2 + f, bf);
    else                  v = ldf(vw, (size_t)(c - 2 * E) * K2 + f, bf);
    unsigned short h = f2bf_bits(v);
    W[idx] = h;
    W[(size_t)total + idx] = f2bf_bits(v - bfbits2f(h));
}

// ---------- out-proj weight prep: hi/lo split-bf16 [E][E] ----------
__global__ void k_woprep(const void* __restrict__ ow, unsigned short* __restrict__ W,
                         const int* __restrict__ dflag, int E)
{
    int bf = *dflag;
    int idx = blockIdx.x * blockDim.x + threadIdx.x;
    int total = E * E;
    if (idx >= total) return;
    float v = ldf(ow, (size_t)idx, bf);
    unsigned short h = f2bf_bits(v);
    W[idx] = h;
    W[(size_t)total + idx] = f2bf_bits(v - bfbits2f(h));
}

// ---------- stitch index map ----------
__device__ __forceinline__ void stitch_map(int y, int x, int s, int nh, int nw,
                                           int& n, int& e)
{
    int px = x % s;
    int d0 = x / s;
    int M  = d0 * (nh * s) + y;
    int py = M / (nw * nh);
    int rem = M - py * (nw * nh);
    int iw = rem / nh;
    int ih = rem - iw * nh;
    n = ih * nw + iw;
    e = py * s + px;
}

// ---------- patchify (+ optional align-corners bilinear up-resize) ----------
__global__ void k_patchify(const void* __restrict__ fp1, const void* __restrict__ fp2,
                           float* __restrict__ qb, float* __restrict__ pb,
                           const int* __restrict__ dflag,
                           int bc0, int chunk, int N, int E, int s, int nh, int nw,
                           int h_, int w_, int h, int w, int resize)
{
    int bf = *dflag;
    int idx = blockIdx.x * blockDim.x + threadIdx.x;
    int total = chunk * N * E;
    if (idx >= total) return;
    int e = idx % E; int t = idx / E;
    int n = t % N;   int i = t / N;
    int ih = n / nw, iw = n - ih * nw;
    int py = e / s,  px = e - py * s;
    int Y = ih * s + py, X = iw * s + px;
    size_t base = (size_t)(bc0 + i) * h_ * w_;
    float v1, v2;
    if (!resize) {
        size_t off = base + (size_t)Y * w_ + X;
        v1 = ldf(fp1, off, bf); v2 = ldf(fp2, off, bf);
    } else {
        float fy = (float)Y * ((float)(h_ - 1) / (float)(h - 1));
        float fx = (float)X * ((float)(w_ - 1) / (float)(w - 1));
        int y0 = (int)floorf(fy); int x0 = (int)floorf(fx);
        float wy = fy - (float)y0, wx = fx - (float)x0;
        int y1 = min(y0 + 1, h_ - 1), x1 = min(x0 + 1, w_ - 1);
        size_t r0 = base + (size_t)y0 * w_, r1 = base + (size_t)y1 * w_;
        {
            float a00 = ldf(fp1, r0 + x0, bf), a01 = ldf(fp1, r0 + x1, bf);
            float a10 = ldf(fp1, r1 + x0, bf), a11 = ldf(fp1, r1 + x1, bf);
            v1 = (a00 * (1.f - wy) + a10 * wy) * (1.f - wx)
               + (a01 * (1.f - wy) + a11 * wy) * wx;
        }
        {
            float a00 = ldf(fp2, r0 + x0, bf), a01 = ldf(fp2, r0 + x1, bf);
            float a10 = ldf(fp2, r1 + x0, bf), a11 = ldf(fp2, r1 + x1, bf);
            v2 = (a00 * (1.f - wy) + a10 * wy) * (1.f - wx)
               + (a01 * (1.f - wy) + a11 * wy) * wx;
        }
    }
    qb[idx] = v1;
    pb[idx] = v2;
}

// ============================================================================
// Split-bf16 MFMA GEMM vs prepped weights (QKV / out-proj).
// C[rows x Ncols] = concat(A1,A2)[rows x Ktot] @ W^T + bias; x = hi + lo, 3 MFMAs.
// mode 0: cols [0,E)->Q row-major, [E,2E)->KB row-major, [2E,3E)->Vt[(i*E+e)*N+n]
// mode 1: OUT row-major [rows x Ncols]
// Tile 64x64, 4 waves (2x2 of 32x32), K-step 32 via mfma_f32_16x16x32_bf16.
// ============================================================================
#define KPAD 40
__global__ __launch_bounds__(256) void
k_mgemm(const float* __restrict__ A1, const float* __restrict__ A2,
        const unsigned short* __restrict__ W, const void* __restrict__ bias,
        float* __restrict__ Q, float* __restrict__ KB, float* __restrict__ Vt,
        float* __restrict__ OUT, const int* __restrict__ dflag,
        int rowsTot, int Ncols, int Ktot, int Esplit, int N, int E, int mode, int ctn)
{
    const int bf = *dflag;
    __shared__ __align__(16) unsigned char smem_raw[20480];
    unsigned short* sAh = (unsigned short*)smem_raw;           // [64][KPAD]
    unsigned short* sAl = sAh + 64 * KPAD;
    unsigned short* sBh = sAl + 64 * KPAD;
    unsigned short* sBl = sBh + 64 * KPAD;
    float* Ct = (float*)smem_raw;                              // [64][66] (epilogue)

    int nwg = gridDim.x;
    int q8 = nwg >> 3, r8 = nwg & 7;
    int xcd = blockIdx.x & 7, bidx = blockIdx.x >> 3;
    int lin = (xcd < r8) ? (xcd * (q8 + 1) + bidx)
                         : (r8 * (q8 + 1) + (xcd - r8) * q8 + bidx);
    int rt = lin / ctn, ct = lin - rt * ctn;
    int row0 = rt * 64, cb0 = ct * 64;

    const int tid = threadIdx.x;
    const int sr = tid >> 2, seg = tid & 3;
    const int lane = tid & 63;
    const int wid = tid >> 6;
    const int wr = wid >> 1, wc = wid & 1;
    const int lr = lane & 15;
    const int lk = (lane >> 4) << 2;

    float4v acc[2][2];
#pragma unroll
    for (int a = 0; a < 2; ++a)
#pragma unroll
        for (int b = 0; b < 2; ++b)
#pragma unroll
            for (int r = 0; r < 4; ++r) acc[a][b][r] = 0.f;

    const int nk = (Ktot + 31) >> 5;
    const int kfast = ((Ktot & 7) == 0);
    const size_t R = (size_t)row0 + sr;
    const bool rok = (row0 + sr) < rowsTot;
    const int strideA2 = Ktot - Esplit;
    const unsigned short* Wl = W + (size_t)Ncols * Ktot;

    for (int kt = 0; kt < nk; ++kt) {
        int k0 = kt << 5;
        {   // stage A [64][32] fp32 -> hi/lo
            int kb = k0 + seg * 8;
            float fv[8];
#pragma unroll
            for (int jj = 0; jj < 2; ++jj) {
                int ks = kb + jj * 4;
                float4 f;
                if (!rok) f = make_float4(0.f, 0.f, 0.f, 0.f);
                else if (ks + 3 < Esplit)
                    f = *(const float4*)(A1 + R * Esplit + ks);
                else if (ks >= Esplit && ks + 3 < Ktot)
                    f = *(const float4*)(A2 + R * (size_t)strideA2 + (ks - Esplit));
                else {
                    float t[4];
#pragma unroll
                    for (int q2 = 0; q2 < 4; ++q2) {
                        int k = ks + q2;
                        t[q2] = (k < Esplit) ? A1[R * Esplit + k]
                              : ((k < Ktot) ? A2[R * (size_t)strideA2 + (k - Esplit)] : 0.f);
                    }
                    f = make_float4(t[0], t[1], t[2], t[3]);
                }
                fv[jj*4+0] = f.x; fv[jj*4+1] = f.y; fv[jj*4+2] = f.z; fv[jj*4+3] = f.w;
            }
            union { uint4 u4; unsigned short us[8]; } ph, pl;
#pragma unroll
            for (int q2 = 0; q2 < 8; ++q2) {
                unsigned short hb = f2bf_bits(fv[q2]);
                ph.us[q2] = hb;
                pl.us[q2] = f2bf_bits(fv[q2] - bfbits2f(hb));
            }
            *(uint4*)&sAh[sr * KPAD + seg * 8] = ph.u4;
            *(uint4*)&sAl[sr * KPAD + seg * 8] = pl.u4;
        }
        {   // stage B [64][32] from prepped hi/lo
            int c = sr, kb = k0 + seg * 8;
            int gc = cb0 + c;
            if (gc < Ncols && kfast && (kb + 7) < Ktot) {
                *(uint4*)&sBh[c * KPAD + seg * 8] = *(const uint4*)(W  + (size_t)gc * Ktot + kb);
                *(uint4*)&sBl[c * KPAD + seg * 8] = *(const uint4*)(Wl + (size_t)gc * Ktot + kb);
            } else {
#pragma unroll
                for (int q2 = 0; q2 < 8; ++q2) {
                    int k = kb + q2;
                    bool ok = (gc < Ncols && k < Ktot);
                    sBh[c * KPAD + seg * 8 + q2] = ok ? W [(size_t)gc * Ktot + k] : (unsigned short)0;
                    sBl[c * KPAD + seg * 8 + q2] = ok ? Wl[(size_t)gc * Ktot + k] : (unsigned short)0;
                }
            }
        }
        __syncthreads();
        union FragU { uint4 u4; short8v s; } fah[2], fal[2], fbh[2], fbl[2];
#pragma unroll
        for (int mr = 0; mr < 2; ++mr) {
            const unsigned short* bh = &sAh[(wr * 32 + mr * 16 + lr) * KPAD + lk];
            uint2 lo = *(const uint2*)bh;  uint2 hi = *(const uint2*)(bh + 16);
            fah[mr].u4 = make_uint4(lo.x, lo.y, hi.x, hi.y);
            const unsigned short* bl = &sAl[(wr * 32 + mr * 16 + lr) * KPAD + lk];
            uint2 lo2 = *(const uint2*)bl; uint2 hi2 = *(const uint2*)(bl + 16);
            fal[mr].u4 = make_uint4(lo2.x, lo2.y, hi2.x, hi2.y);
        }
#pragma unroll
        for (int nc = 0; nc < 2; ++nc) {
            const unsigned short* bh = &sBh[(wc * 32 + nc * 16 + lr) * KPAD + lk];
            uint2 lo = *(const uint2*)bh;  uint2 hi = *(const uint2*)(bh + 16);
            fbh[nc].u4 = make_uint4(lo.x, lo.y, hi.x, hi.y);
            const unsigned short* bl = &sBl[(wc * 32 + nc * 16 + lr) * KPAD + lk];
            uint2 lo2 = *(const uint2*)bl; uint2 hi2 = *(const uint2*)(bl + 16);
            fbl[nc].u4 = make_uint4(lo2.x, lo2.y, hi2.x, hi2.y);
        }
#pragma unroll
        for (int mr = 0; mr < 2; ++mr)
#pragma unroll
            for (int nc = 0; nc < 2; ++nc) {
                acc[mr][nc] = __builtin_amdgcn_mfma_f32_16x16x32_bf16(
                    fah[mr].s, fbl[nc].s, acc[mr][nc], 0, 0, 0);
                acc[mr][nc] = __builtin_amdgcn_mfma_f32_16x16x32_bf16(
                    fal[mr].s, fbh[nc].s, acc[mr][nc], 0, 0, 0);
                acc[mr][nc] = __builtin_amdgcn_mfma_f32_16x16x32_bf16(
                    fah[mr].s, fbh[nc].s, acc[mr][nc], 0, 0, 0);
            }
        __syncthreads();
    }

    // epilogue: bias, stage through LDS, routed stores
#pragma unroll
    for (int mr = 0; mr < 2; ++mr)
#pragma unroll
        for (int nc = 0; nc < 2; ++nc) {
            int cloc = wc * 32 + nc * 16 + lr;
            int gc = cb0 + cloc;
            float bv = (gc < Ncols) ? ldf(bias, (size_t)gc, bf) : 0.f;
#pragma unroll
            for (int r = 0; r < 4; ++r) {
                int rloc = wr * 32 + mr * 16 + ((lane >> 4) << 2) + r;
                Ct[rloc * 66 + cloc] = acc[mr][nc][r] + bv;
            }
        }
    __syncthreads();

    if (mode == 1) {
#pragma unroll
        for (int p = 0; p < 16; ++p) {
            int r = p * 4 + (tid >> 6);
            int cL = tid & 63;
            int gc = cb0 + cL;
            int gr = row0 + r;
            if (gr < rowsTot && gc < Ncols)
                OUT[(size_t)gr * Ncols + gc] = Ct[r * 66 + cL];
        }
    } else {
        // Q and K: row-major
#pragma unroll
        for (int p = 0; p < 16; ++p) {
            int r = p * 4 + (tid >> 6);
            int cL = tid & 63;
            int gc = cb0 + cL;
            int gr = row0 + r;
            if (gr < rowsTot && gc < Ncols) {
                float v = Ct[r * 66 + cL];
                if (gc < E)            Q[(size_t)gr * E + gc] = v;
                else if (gc < 2 * E)   KB[(size_t)gr * E + (gc - E)] = v;
            }
        }
        // V: transposed per item, coalesced along n
#pragma unroll
        for (int p = 0; p < 16; ++p) {
            int cL = p * 4 + (tid >> 6);
            int r = tid & 63;
            int gc = cb0 + cL;
            int gr = row0 + r;
            if (gr < rowsTot && gc >= 2 * E && gc < Ncols) {
                int i = gr / N, n = gr - i * N;
                Vt[((size_t)i * E + (gc - 2 * E)) * N + n] = Ct[r * 66 + cL];
            }
        }
    }
}

// ============================================================================
// Batched split-bf16 MFMA GEMM: per item i,
//   C_i[M x Ncols] = alpha * A_i[M x Ktot] @ B_i^T   (B_i stored [Ncols x Ktot])
// ============================================================================
__global__ __launch_bounds__(256) void
k_bgemm(const float* __restrict__ A, const float* __restrict__ B, float* __restrict__ C,
        int M, int Ncols, int Ktot, float alpha, int mt, int ctn)
{
    __shared__ __align__(16) unsigned char smem_raw[20480];
    unsigned short* sAh = (unsigned short*)smem_raw;
    unsigned short* sAl = sAh + 64 * KPAD;
    unsigned short* sBh = sAl + 64 * KPAD;
    unsigned short* sBl = sBh + 64 * KPAD;
    float* Ct = (float*)smem_raw;

    int nwg = gridDim.x;
    int q8 = nwg >> 3, r8 = nwg & 7;
    int xcd = blockIdx.x & 7, bidx = blockIdx.x >> 3;
    int lin = (xcd < r8) ? (xcd * (q8 + 1) + bidx)
                         : (r8 * (q8 + 1) + (xcd - r8) * q8 + bidx);
    int per_item = mt * ctn;
    int item = lin / per_item;
    int tt = lin - item * per_item;
    int rt = tt / ctn, ct = tt - rt * ctn;
    int row0 = rt * 64, cb0 = ct * 64;

    const float* Ai = A + (size_t)item * M * Ktot;
    const float* Bi = B + (size_t)item * Ncols * Ktot;
    float* Ci = C + (size_t)item * M * Ncols;

    const int tid = threadIdx.x;
    const int sr = tid >> 2, seg = tid & 3;
    const int lane = tid & 63, wid = tid >> 6;
    const int wr = wid >> 1, wc = wid & 1;
    const int lr = lane & 15, lk = (lane >> 4) << 2;

    float4v acc[2][2];
#pragma unroll
    for (int a = 0; a < 2; ++a)
#pragma unroll
        for (int b = 0; b < 2; ++b)
#pragma unroll
            for (int r = 0; r < 4; ++r) acc[a][b][r] = 0.f;

    const int nk = (Ktot + 31) >> 5;
    const int kvec = ((Ktot & 3) == 0);
    const bool arok = (row0 + sr) < M;
    const bool brok = (cb0 + sr) < Ncols;
    const float* Arow = Ai + (size_t)(row0 + sr) * Ktot;
    const float* Brow = Bi + (size_t)(cb0 + sr) * Ktot;

    for (int kt = 0; kt < nk; ++kt) {
        int kb = (kt << 5) + seg * 8;
        {   // stage A
            float fv[8];
#pragma unroll
            for (int jj = 0; jj < 2; ++jj) {
                int ks = kb + jj * 4;
                if (arok && kvec && (ks + 3) < Ktot) {
                    float4 f = *(const float4*)(Arow + ks);
                    fv[jj*4+0] = f.x; fv[jj*4+1] = f.y; fv[jj*4+2] = f.z; fv[jj*4+3] = f.w;
                } else {
#pragma unroll
                    for (int q2 = 0; q2 < 4; ++q2) {
                        int k = ks + q2;
                        fv[jj*4+q2] = (arok && k < Ktot) ? Arow[k] : 0.f;
                    }
                }
            }
            union { uint4 u4; unsigned short us[8]; } ph, pl;
#pragma unroll
            for (int q2 = 0; q2 < 8; ++q2) {
                unsigned short hb = f2bf_bits(fv[q2]);
                ph.us[q2] = hb;
                pl.us[q2] = f2bf_bits(fv[q2] - bfbits2f(hb));
            }
            *(uint4*)&sAh[sr * KPAD + seg * 8] = ph.u4;
            *(uint4*)&sAl[sr * KPAD + seg * 8] = pl.u4;
        }
        {   // stage B
            float fv[8];
#pragma unroll
            for (int jj = 0; jj < 2; ++jj) {
                int ks = kb + jj * 4;
                if (brok && kvec && (ks + 3) < Ktot) {
                    float4 f = *(const float4*)(Brow + ks);
                    fv[jj*4+0] = f.x; fv[jj*4+1] = f.y; fv[jj*4+2] = f.z; fv[jj*4+3] = f.w;
                } else {
#pragma unroll
                    for (int q2 = 0; q2 < 4; ++q2) {
                        int k = ks + q2;
                        fv[jj*4+q2] = (brok && k < Ktot) ? Brow[k] : 0.f;
                    }
                }
            }
            union { uint4 u4; unsigned short us[8]; } ph, pl;
#pragma unroll
            for (int q2 = 0; q2 < 8; ++q2) {
                unsigned short hb = f2bf_bits(fv[q2]);
                ph.us[q2] = hb;
                pl.us[q2] = f2bf_bits(fv[q2] - bfbits2f(hb));
            }
            *(uint4*)&sBh[sr * KPAD + seg * 8] = ph.u4;
            *(uint4*)&sBl[sr * KPAD + seg * 8] = pl.u4;
        }
        __syncthreads();
        union FragU { uint4 u4; short8v s; } fah[2], fal[2], fbh[2], fbl[2];
#pragma unroll
        for (int mr = 0; mr < 2; ++mr) {
            const unsigned short* bh = &sAh[(wr * 32 + mr * 16 + lr) * KPAD + lk];
            uint2 lo = *(const uint2*)bh;  uint2 hi = *(const uint2*)(bh + 16);
            fah[mr].u4 = make_uint4(lo.x, lo.y, hi.x, hi.y);
            const unsigned short* bl = &sAl[(wr * 32 + mr * 16 + lr) * KPAD + lk];
            uint2 lo2 = *(const uint2*)bl; uint2 hi2 = *(const uint2*)(bl + 16);
            fal[mr].u4 = make_uint4(lo2.x, lo2.y, hi2.x, hi2.y);
        }
#pragma unroll
        for (int nc = 0; nc < 2; ++nc) {
            const unsigned short* bh = &sBh[(wc * 32 + nc * 16 + lr) * KPAD + lk];
            uint2 lo = *(const uint2*)bh;  uint2 hi = *(const uint2*)(bh + 16);
            fbh[nc].u4 = make_uint4(lo.x, lo.y, hi.x, hi.y);
            const unsigned short* bl = &sBl[(wc * 32 + nc * 16 + lr) * KPAD + lk];
            uint2 lo2 = *(const uint2*)bl; uint2 hi2 = *(const uint2*)(bl + 16);
            fbl[nc].u4 = make_uint4(lo2.x, lo2.y, hi2.x, hi2.y);
        }
#pragma unroll
        for (int mr = 0; mr < 2; ++mr)
#pragma unroll
            for (int nc = 0; nc < 2; ++nc) {
                acc[mr][nc] = __builtin_amdgcn_mfma_f32_16x16x32_bf16(
                    fah[mr].s, fbl[nc].s, acc[mr][nc], 0, 0, 0);
                acc[mr][nc] = __builtin_amdgcn_mfma_f32_16x16x32_bf16(
                    fal[mr].s, fbh[nc].s, acc[mr][nc], 0, 0, 0);
                acc[mr][nc] = __builtin_amdgcn_mfma_f32_16x16x32_bf16(
                    fah[mr].s, fbh[nc].s, acc[mr][nc], 0, 0, 0);
            }
        __syncthreads();
    }

#pragma unroll
    for (int mr = 0; mr < 2; ++mr)
#pragma unroll
        for (int nc = 0; nc < 2; ++nc) {
            int cloc = wc * 32 + nc * 16 + lr;
#pragma unroll
            for (int r = 0; r < 4; ++r) {
                int rloc = wr * 32 + mr * 16 + ((lane >> 4) << 2) + r;
                Ct[rloc * 66 + cloc] = acc[mr][nc][r] * alpha;
            }
        }
    __syncthreads();
#pragma unroll
    for (int p = 0; p < 16; ++p) {
        int r = p * 4 + (tid >> 6);
        int cL = tid & 63;
        int gr = row0 + r, gc = cb0 + cL;
        if (gr < M && gc < Ncols)
            Ci[(size_t)gr * Ncols + gc] = Ct[r * 66 + cL];
    }
}

// ---------- softmax rows in place (wave per row, shuffle-only) ----------
__global__ void k_softmax(float* __restrict__ S, int rowsTot, int N)
{
    int lane = threadIdx.x & 63;
    int row = blockIdx.x * (blockDim.x >> 6) + (threadIdx.x >> 6);
    if (row >= rowsTot) return;
    float* rp = S + (size_t)row * N;
    float v[4];
    float mx = -3.0e38f;
#pragma unroll
    for (int j = 0; j < 4; ++j) {
        int e = lane + j * 64;
        v[j] = (e < N) ? rp[e] : -3.0e38f;
        mx = fmaxf(mx, v[j]);
    }
#pragma unroll
    for (int off = 32; off; off >>= 1) mx = fmaxf(mx, __shfl_xor(mx, off));
    float s = 0.f;
#pragma unroll
    for (int j = 0; j < 4; ++j) {
        int e = lane + j * 64;
        v[j] = (e < N) ? __expf(v[j] - mx) : 0.f;
        s += v[j];
    }
#pragma unroll
    for (int off = 32; off; off >>= 1) s += __shfl_xor(s, off);
    float inv = 1.f / s;
#pragma unroll
    for (int j = 0; j < 4; ++j) {
        int e = lane + j * 64;
        if (e < N) rp[e] = v[j] * inv;
    }
}

// ---------- LayerNorm rows (wave per row) ----------
__global__ void k_ln(const float* __restrict__ X, float* __restrict__ Y,
                     const void* __restrict__ lng, const void* __restrict__ lnb,
                     const int* __restrict__ dflag, int rowsTot, int E)
{
    int bf = *dflag;
    int lane = threadIdx.x & 63;
    int wpb = blockDim.x >> 6;
    int wid = (blockIdx.x * wpb) + (threadIdx.x >> 6);
    int nw = gridDim.x * wpb;
    for (int row = wid; row < rowsTot; row += nw) {
        const float* xr = X + (size_t)row * E;
        float s = 0.f, s2 = 0.f;
        for (int e = lane; e < E; e += 64) { float v = xr[e]; s += v; s2 += v * v; }
#pragma unroll
        for (int off = 32; off; off >>= 1) {
            s  += __shfl_xor(s, off);
            s2 += __shfl_xor(s2, off);
        }
        float mu  = s / (float)E;
        float var = s2 / (float)E - mu * mu;
        float inv = rsqrtf(var + 1e-5f);
        float* yr = Y + (size_t)row * E;
        for (int e = lane; e < E; e += 64) {
            float g = ldf(lng, e, bf), b = ldf(lnb, e, bf);
            yr[e] = (xr[e] - mu) * inv * g + b;
        }
    }
}

// ---------- final blend, no-resize levels ----------
__global__ void k_final(const float* __restrict__ O2,
                        const void* __restrict__ fp1, const void* __restrict__ fp2,
                        const void* __restrict__ logits, void* __restrict__ out,
                        const int* __restrict__ dflag, size_t obase,
                        int bc0, int chunk, int h, int w, int s, int nh, int nw,
                        int N, int E)
{
    int bf = *dflag;
    int idx = blockIdx.x * blockDim.x + threadIdx.x;
    int total = chunk * h * w;
    if (idx >= total) return;
    int x = idx % w; int t = idx / w;
    int y = t % h;   int i = t / h;
    int n, e;
    stitch_map(y, x, s, nh, nw, n, e);
    float fus = O2[((size_t)i * N + n) * E + e];
    float l0 = ldf(logits, 0, bf), l1 = ldf(logits, 1, bf), l2 = ldf(logits, 2, bf);
    float mx = fmaxf(l0, fmaxf(l1, l2));
    float e0 = __expf(l0 - mx), e1 = __expf(l1 - mx), e2 = __expf(l2 - mx);
    float inv = 1.f / (e0 + e1 + e2);
    size_t off = ((size_t)(bc0 + i) * h + y) * w + x;
    float v = ldf(fp1, off, bf) * (e0 * inv) + ldf(fp2, off, bf) * (e1 * inv)
            + fus * (e2 * inv);
    stf(out, obase + off, bf, v);
}

// ---------- stitch to full (rounded) grid, fp32 (p3 only) ----------
__global__ void k_stitch(const float* __restrict__ O2, float* __restrict__ st,
                         int chunk, int h, int w, int s, int nh, int nw, int N, int E)
{
    int idx = blockIdx.x * blockDim.x + threadIdx.x;
    int total = chunk * h * w;
    if (idx >= total) return;
    int x = idx % w; int t = idx / w;
    int y = t % h;   int i = t / h;
    int n, e;
    stitch_map(y, x, s, nh, nw, n, e);
    st[idx] = O2[((size_t)i * N + n) * E + e];
}

// ---------- down-resize (align corners) + blend (p3 only) ----------
__global__ void k_rblend(const float* __restrict__ st,
                         const void* __restrict__ fp1, const void* __restrict__ fp2,
                         const void* __restrict__ logits, void* __restrict__ out,
                         const int* __restrict__ dflag, size_t obase,
                         int bc0, int chunk, int h_, int w_, int h, int w)
{
    int bf = *dflag;
    int idx = blockIdx.x * blockDim.x + threadIdx.x;
    int total = chunk * h_ * w_;
    if (idx >= total) return;
    int x = idx % w_; int t = idx / w_;
    int y = t % h_;   int i = t / h_;
    float fy = (float)y * ((float)(h - 1) / (float)(h_ - 1));
    float fx = (float)x * ((float)(w - 1) / (float)(w_ - 1));
    int y0 = (int)floorf(fy); int x0 = (int)floorf(fx);
    float wy = fy - (float)y0, wx = fx - (float)x0;
    int y1 = min(y0 + 1, h - 1), x1 = min(x0 + 1, w - 1);
    size_t base = (size_t)i * h * w;
    float a00 = st[base + (size_t)y0 * w + x0], a01 = st[base + (size_t)y0 * w + x1];
    float a10 = st[base + (size_t)y1 * w + x0], a11 = st[base + (size_t)y1 * w + x1];
    float fus = (a00 * (1.f - wy) + a10 * wy) * (1.f - wx)
              + (a01 * (1.f - wy) + a11 * wy) * wx;
    float l0 = ldf(logits, 0, bf), l1 = ldf(logits, 1, bf), l2 = ldf(logits, 2, bf);
    float mx = fmaxf(l0, fmaxf(l1, l2));
    float e0 = __expf(l0 - mx), e1 = __expf(l1 - mx), e2 = __expf(l2 - mx);
    float inv = 1.f / (e0 + e1 + e2);
    size_t off = ((size_t)(bc0 + i) * h_ + y) * w_ + x;
    float v = ldf(fp1, off, bf) * (e0 * inv) + ldf(fp2, off, bf) * (e1 * inv)
            + fus * (e2 * inv);
    stf(out, obase + off, bf, v);
}

extern "C" void kernel_launch(void* const* d_in, const int* in_sizes, int n_in,
                              void* d_out, int out_size, void* d_ws, size_t ws_size,
                              hipStream_t stream)
{
    (void)in_sizes; (void)n_in; (void)out_size;
    const void* FP1[5]; const void* FP2[5];
    const void *QW[5], *KW[5], *VW[5], *INB[5], *OW[5], *OB[5], *LNG[5], *LNB[5];
    for (int l = 0; l < 5; ++l) {
        FP1[l] = d_in[l];
        FP2[l] = d_in[5 + l];
        int b = 10 + 8 * l;
        QW[l]  = d_in[b + 0];
        KW[l]  = d_in[b + 1];
        VW[l]  = d_in[b + 2];
        INB[l] = d_in[b + 3];
        OW[l]  = d_in[b + 4];
        OB[l]  = d_in[b + 5];
        LNG[l] = d_in[b + 6];
        LNB[l] = d_in[b + 7];
    }
    const void* logits = d_in[50];
    void* out = d_out;

    static const int HH[5] = {256, 128, 64, 32, 16};
    static const int SS[5] = {16, 12, 8, 4, 2};

    // ws layout: [6 fp32 slots][2.5MB weight region][dtype flag (16B)]
    size_t flag_off = (ws_size - 16) & ~(size_t)15;
    int* dflag = (int*)((char*)d_ws + flag_off);
    const size_t WRES = (size_t)2621440;
    size_t wreg_off = (flag_off > WRES) ? ((flag_off - WRES) & ~(size_t)255) : 0;
    size_t slot_bytes = (wreg_off / 6) & ~(size_t)255;
    size_t slot_elems = slot_bytes / sizeof(float);
    float* slot[6];
    for (int i = 0; i < 6; ++i) slot[i] = (float*)((char*)d_ws + (size_t)i * slot_bytes);

    k_detect<<<1, 64, 0, stream>>>(FP1[0], dflag);

    size_t ooff = 0;
    for (int l = 0; l < 5; ++l) {
        int h_ = HH[l], w_ = HH[l], s = SS[l];
        int nh = (h_ % s == 0) ? (h_ / s) : (h_ / s + 1);
        int nw = nh;
        int h = nh * s, w = nw * s;
        int N = nh * nw, E = s * s;
        int resize = (h != h_) ? 1 : 0;
        float scale = 1.0f / sqrtf((float)E);
        size_t maxNE = (size_t)N * (size_t)((E > N) ? E : N);

        // per-level weight prep: hi/lo split-bf16
        unsigned short* WcP = (unsigned short*)((char*)d_ws + wreg_off);
        unsigned short* WoP = WcP + (size_t)2 * 3 * E * 2 * E;
        {
            int tpb = 256;
            k_wprep<<<(3 * E * 2 * E + tpb - 1) / tpb, tpb, 0, stream>>>(QW[l], KW[l], VW[l], WcP, dflag, E);
            k_woprep<<<(E * E + tpb - 1) / tpb, tpb, 0, stream>>>(OW[l], WoP, dflag, E);
        }

        int chunk = 512;
        size_t c = (maxNE > 0) ? (slot_elems / maxNE) : 0;
        if (c < 512) { int p = 1; while ((size_t)(p << 1) <= c) p <<= 1; chunk = p; }
        int nchunks = 512 / chunk;

        for (int cidx = 0; cidx < nchunks; ++cidx) {
            int bc0 = cidx * chunk;
            int rows = chunk * N;
            // 1) patchify
            {
                int tot = chunk * N * E, tpb = 256, g = (tot + tpb - 1) / tpb;
                k_patchify<<<g, tpb, 0, stream>>>(FP1[l], FP2[l], slot[0], slot[1],
                                                  dflag, bc0, chunk, N, E, s, nh, nw,
                                                  h_, w_, h, w, resize);
            }
            // 2) QKV via split-bf16 MFMA -> Q (slot2), K row-major (slot3), Vt (slot4)
            {
                int rt = (rows + 63) / 64, ctn = (3 * E + 63) / 64;
                k_mgemm<<<rt * ctn, 256, 0, stream>>>(slot[0], slot[1], WcP, INB[l],
                                                      slot[2], slot[3], slot[4], nullptr,
                                                      dflag, rows, 3 * E, 2 * E, E, N, E, 0, ctn);
            }
            // 3) S = scale * Q K^T (batched MFMA), softmax in place
            {
                int mt = (N + 63) / 64, cts = (N + 63) / 64;
                k_bgemm<<<chunk * mt * cts, 256, 0, stream>>>(slot[2], slot[3], slot[5],
                                                              N, N, E, scale, mt, cts);
                k_softmax<<<(rows + 3) / 4, 256, 0, stream>>>(slot[5], rows, N);
            }
            // 4) O = P V (batched MFMA) -> slot0
            {
                int mt = (N + 63) / 64, cte = (E + 63) / 64;
                k_bgemm<<<chunk * mt * cte, 256, 0, stream>>>(slot[5], slot[4], slot[0],
                                                              N, E, N, 1.0f, mt, cte);
            }
            // 5) out-proj via split-bf16 MFMA, then LN
            {
                int rt = (rows + 63) / 64, ctn = (E + 63) / 64;
                k_mgemm<<<rt * ctn, 256, 0, stream>>>(slot[0], slot[0], WoP, OB[l],
                                                      nullptr, nullptr, nullptr, slot[5],
                                                      dflag, rows, E, E, E, N, E, 1, ctn);
                int gb = (rows + 3) / 4; if (gb > 2048) gb = 2048;
                k_ln<<<gb, 256, 0, stream>>>(slot[5], slot[1], LNG[l], LNB[l], dflag, rows, E);
            }
            // 6) stitch (+resize) + blend
            if (!resize) {
                int tot = chunk * h * w, tpb = 256, g = (tot + tpb - 1) / tpb;
                k_final<<<g, tpb, 0, stream>>>(slot[1], FP1[l], FP2[l], logits, out,
                                               dflag, ooff, bc0, chunk, h, w, s, nh, nw, N, E);
            } else {
                int tot = chunk * h * w, tpb = 256, g = (tot + tpb - 1) / tpb;
                k_stitch<<<g, tpb, 0, stream>>>(slot[1], slot[2], chunk, h, w, s, nh, nw, N, E);
                int tot2 = chunk * h_ * w_, g2 = (tot2 + tpb - 1) / tpb;
                k_rblend<<<g2, tpb, 0, stream>>>(slot[2], FP1[l], FP2[l], logits, out,
                                                 dflag, ooff, bc0, chunk, h_, w_, h, w);
            }
        }
        ooff += (size_t)512 * h_ * w_;
    }
}